// Round 2
// baseline (3997.514 us; speedup 1.0000x reference)
//
#include <hip/hip_runtime.h>
#include <hip/hip_bf16.h>
#include <math.h>

#define BATCH 2
#define SEQ 4096
#define DMODEL 1024
#define NH 4
#define DHEAD 256
#define NCHUNK 128
#define ROWS (BATCH * SEQ) /* 8192 */

__device__ __forceinline__ float sigm(float x) { return 1.0f / (1.0f + expf(-x)); }
__device__ __forceinline__ float siluf(float x) { return x / (1.0f + expf(-x)); }

/* ---------------- generic f32 GEMM: C = A(MxK) * B(KxN) [+bias][+gelu][bf16 out] ----
   BM=BN=128, BK=8, 256 threads, 8x8 per thread. M%128==0, N%128==0, K%8==0. */
template <int ACT, bool BF16OUT>
__global__ __launch_bounds__(256) void gemm_t(
    const float* __restrict__ A, const float* __restrict__ Bm,
    const float* __restrict__ bias, void* __restrict__ Cv,
    int M, int N, int K) {
  __shared__ float As[8][128];
  __shared__ float Bs[8][128];
  const int t = threadIdx.x;
  const int row0 = blockIdx.y * 128;
  const int col0 = blockIdx.x * 128;
  const int tm = (t >> 4) * 8;
  const int tn = (t & 15) * 8;
  const int arow = t >> 1;
  const int acol = (t & 1) * 4;
  const int brow = t >> 5;
  const int bcol = (t & 31) * 4;
  const float* Aptr = A + (long)(row0 + arow) * K + acol;
  const float* Bptr = Bm + (long)brow * N + col0 + bcol;
  float acc[8][8];
#pragma unroll
  for (int i = 0; i < 8; ++i)
#pragma unroll
    for (int j = 0; j < 8; ++j) acc[i][j] = 0.f;
  for (int k0 = 0; k0 < K; k0 += 8) {
    float4 a4 = *(const float4*)(Aptr + k0);
    float4 b4 = *(const float4*)(Bptr + (long)k0 * N);
    As[acol + 0][arow] = a4.x;
    As[acol + 1][arow] = a4.y;
    As[acol + 2][arow] = a4.z;
    As[acol + 3][arow] = a4.w;
    *(float4*)&Bs[brow][bcol] = b4;
    __syncthreads();
#pragma unroll
    for (int kk = 0; kk < 8; ++kk) {
      float4 a0 = *(const float4*)&As[kk][tm];
      float4 a1 = *(const float4*)&As[kk][tm + 4];
      float4 b0 = *(const float4*)&Bs[kk][tn];
      float4 b1 = *(const float4*)&Bs[kk][tn + 4];
      float av[8] = {a0.x, a0.y, a0.z, a0.w, a1.x, a1.y, a1.z, a1.w};
      float bv[8] = {b0.x, b0.y, b0.z, b0.w, b1.x, b1.y, b1.z, b1.w};
#pragma unroll
      for (int i = 0; i < 8; ++i)
#pragma unroll
        for (int j = 0; j < 8; ++j) acc[i][j] = fmaf(av[i], bv[j], acc[i][j]);
    }
    __syncthreads();
  }
#pragma unroll
  for (int i = 0; i < 8; ++i) {
    float out[8];
#pragma unroll
    for (int j = 0; j < 8; ++j) {
      float v = acc[i][j];
      if (bias) v += bias[col0 + tn + j];
      if (ACT == 1) v = 0.5f * v * (1.0f + erff(v * 0.70710678118654752f));
      out[j] = v;
    }
    if (BF16OUT) {
      __hip_bfloat16* Crow = (__hip_bfloat16*)Cv + (long)(row0 + tm + i) * N + col0 + tn;
#pragma unroll
      for (int j = 0; j < 8; ++j) Crow[j] = __float2bfloat16(out[j]);
    } else {
      float* Crow = (float*)Cv + (long)(row0 + tm + i) * N + col0 + tn;
      *(float4*)(Crow) = make_float4(out[0], out[1], out[2], out[3]);
      *(float4*)(Crow + 4) = make_float4(out[4], out[5], out[6], out[7]);
    }
  }
}

/* ---------- beta = sigmoid(x@Wb), idsc = 0.06 + sig(alpha)*sig(x@Wid + bid) ---------- */
__global__ __launch_bounds__(256) void rowdot8(
    const float* __restrict__ x, const float* __restrict__ Wb,
    const float* __restrict__ Wid, const float* __restrict__ alpha_id,
    const float* __restrict__ bidp, float* __restrict__ beta, float* __restrict__ idsc) {
  const int row = blockIdx.x;
  const int t = threadIdx.x;
  const float* xr = x + (long)row * DMODEL;
  float ab[4] = {0, 0, 0, 0}, ai[4] = {0, 0, 0, 0};
  for (int k = t; k < DMODEL; k += 256) {
    float xv = xr[k];
    float4 wb = *(const float4*)(Wb + k * 4);
    float4 wi = *(const float4*)(Wid + k * 4);
    ab[0] = fmaf(xv, wb.x, ab[0]); ab[1] = fmaf(xv, wb.y, ab[1]);
    ab[2] = fmaf(xv, wb.z, ab[2]); ab[3] = fmaf(xv, wb.w, ab[3]);
    ai[0] = fmaf(xv, wi.x, ai[0]); ai[1] = fmaf(xv, wi.y, ai[1]);
    ai[2] = fmaf(xv, wi.z, ai[2]); ai[3] = fmaf(xv, wi.w, ai[3]);
  }
#pragma unroll
  for (int m = 1; m < 64; m <<= 1) {
#pragma unroll
    for (int hh = 0; hh < 4; ++hh) {
      ab[hh] += __shfl_xor(ab[hh], m);
      ai[hh] += __shfl_xor(ai[hh], m);
    }
  }
  __shared__ float red[4][8];
  if ((t & 63) == 0) {
    int wv = t >> 6;
#pragma unroll
    for (int hh = 0; hh < 4; ++hh) {
      red[wv][hh] = ab[hh];
      red[wv][4 + hh] = ai[hh];
    }
  }
  __syncthreads();
  if (t < 8) {
    float s = red[0][t] + red[1][t] + red[2][t] + red[3][t];
    if (t < 4) {
      beta[(long)row * NH + t] = sigm(s);
    } else {
      int hh = t - 4;
      idsc[(long)row * NH + hh] = 0.06f + sigm(alpha_id[hh]) * sigm(s + bidp[hh]);
    }
  }
}

/* ---------- causal depthwise conv (K=4) + silu, single plane ---------- */
__global__ __launch_bounds__(256) void conv_silu(
    const float* __restrict__ pre, const float* __restrict__ cw, float* __restrict__ out) {
  const int row = blockIdx.x;
  const int l = row & (SEQ - 1);
  const int t = threadIdx.x;
  const int cb = t * 4;
  float wts[4][4];
#pragma unroll
  for (int cc = 0; cc < 4; ++cc) {
    float4 w4 = *(const float4*)(cw + (cb + cc) * 4);
    wts[cc][0] = w4.x; wts[cc][1] = w4.y; wts[cc][2] = w4.z; wts[cc][3] = w4.w;
  }
  float acc[4] = {0, 0, 0, 0};
#pragma unroll
  for (int tap = 0; tap < 4; ++tap) {
    int lr = l - 3 + tap;
    if (lr >= 0) {
      float4 xv = *(const float4*)(pre + (long)(row - 3 + tap) * DMODEL + cb);
      acc[0] = fmaf(wts[0][tap], xv.x, acc[0]);
      acc[1] = fmaf(wts[1][tap], xv.y, acc[1]);
      acc[2] = fmaf(wts[2][tap], xv.z, acc[2]);
      acc[3] = fmaf(wts[3][tap], xv.w, acc[3]);
    }
  }
  float4 ov = make_float4(siluf(acc[0]), siluf(acc[1]), siluf(acc[2]), siluf(acc[3]));
  *(float4*)(out + (long)row * DMODEL + cb) = ov;
}

/* ---------- in-place l2norm of q,k per (row, head); one wave per unit ---------- */
__global__ __launch_bounds__(256) void l2norm_qk(float* __restrict__ q, float* __restrict__ k) {
  const int t = threadIdx.x;
  const int unit = blockIdx.x * 4 + (t >> 6);
  const int lane = t & 63;
  const int row = unit >> 2;
  const int h = unit & 3;
  const long base = (long)row * DMODEL + h * DHEAD + lane * 4;
  float4 q4 = *(const float4*)(q + base);
  float4 k4 = *(const float4*)(k + base);
  float sq = q4.x * q4.x + q4.y * q4.y + q4.z * q4.z + q4.w * q4.w;
  float sk = k4.x * k4.x + k4.y * k4.y + k4.z * k4.z + k4.w * k4.w;
#pragma unroll
  for (int m = 1; m < 64; m <<= 1) {
    sq += __shfl_xor(sq, m);
    sk += __shfl_xor(sk, m);
  }
  float rq = rsqrtf(sq + 1e-6f);
  float rk = rsqrtf(sk + 1e-6f);
  q4.x *= rq; q4.y *= rq; q4.z *= rq; q4.w *= rq;
  k4.x *= rk; k4.y *= rk; k4.z *= rk; k4.w *= rk;
  *(float4*)(q + base) = q4;
  *(float4*)(k + base) = k4;
}

/* ---------- phase A: per-chunk T solve, u=T'v, w=T'k, attn. block per (b,h,chunk) ---------- */
__global__ __launch_bounds__(256) void phaseA(
    const float* __restrict__ qn, const float* __restrict__ kn, const float* __restrict__ v,
    const float* __restrict__ beta, float* __restrict__ u, float* __restrict__ w,
    float* __restrict__ attn_g) {
  __shared__ float Ks[32][256];
  __shared__ float T[32][33];
  __shared__ float bet[32];
  const int bid = blockIdx.x;
  const int c = bid & (NCHUNK - 1);
  const int h = (bid >> 7) & 3;
  const int b = bid >> 9;
  const int bh = b * NH + h;
  const int l0 = c * 32;
  const int t = threadIdx.x;
  const int wv = t >> 6;
  const int lane = t & 63;

#pragma unroll
  for (int r = 0; r < 8; ++r) {
    int idx = t + 256 * r;
    int i = idx >> 6;
    int f = (idx & 63) * 4;
    long gq = ((long)(b * SEQ + l0 + i)) * DMODEL + h * DHEAD + f;
    *(float4*)&Ks[i][f] = *(const float4*)(kn + gq);
  }
  if (t < 32) bet[t] = beta[(long)(b * SEQ + l0 + t) * NH + h];
  __syncthreads();

  /* T = strict-lower(-(kb kn^T)) : wave-parallel dot per entry */
  {
#pragma unroll
    for (int ii = 0; ii < 8; ++ii) {
      const int i = wv * 8 + ii;
      float4 a = *(const float4*)&Ks[i][lane * 4];
      float nbi = -bet[i];
      for (int j = 0; j < 32; ++j) {
        float val = 0.f;
        if (j < i) {
          float4 bb = *(const float4*)&Ks[j][lane * 4];
          float pd = a.x * bb.x + a.y * bb.y + a.z * bb.z + a.w * bb.w;
#pragma unroll
          for (int m = 1; m < 64; m <<= 1) pd += __shfl_xor(pd, m);
          val = nbi * pd;
        }
        if (lane == 0) T[i][j] = val;
      }
    }
  }
  __syncthreads();

  /* forward substitution (rows in order, lockstep within wave 0) + add I + fold beta */
  if (t < 32) {
    const int l = t;
    for (int i = 1; i < 32; ++i) {
      float s = 0.f;
      for (int j = 0; j < i; ++j) s = fmaf(T[i][j], T[j][l], s);
      T[i][l] += s;
    }
    for (int i = 0; i < 32; ++i) {
      float val = T[i][l] + (i == l ? 1.f : 0.f);
      T[i][l] = val * bet[l];
    }
  }
  __syncthreads();

  /* u = T' @ v, w = T' @ kn ; thread = column d */
  {
    const int d = t;
    float acc[32];
#pragma unroll
    for (int i = 0; i < 32; ++i) acc[i] = 0.f;
    for (int j = 0; j < 32; ++j) {
      float vv = v[((long)(b * SEQ + l0 + j)) * DMODEL + h * DHEAD + d];
#pragma unroll
      for (int i = 0; i < 32; ++i) acc[i] = fmaf(T[i][j], vv, acc[i]);
    }
    long ubase = ((long)bh * SEQ + l0) * DHEAD + d;
#pragma unroll
    for (int i = 0; i < 32; ++i) u[ubase + (long)i * DHEAD] = acc[i];
#pragma unroll
    for (int i = 0; i < 32; ++i) acc[i] = 0.f;
    for (int j = 0; j < 32; ++j) {
      float kv = Ks[j][d];
#pragma unroll
      for (int i = 0; i < 32; ++i) acc[i] = fmaf(T[i][j], kv, acc[i]);
    }
#pragma unroll
    for (int i = 0; i < 32; ++i) w[ubase + (long)i * DHEAD] = acc[i];
  }
  __syncthreads();

  /* attn = tril(qn kn^T) incl diag */
  {
    long abase = ((long)bh * NCHUNK + c) * 1024;
#pragma unroll
    for (int ii = 0; ii < 8; ++ii) {
      const int i = wv * 8 + ii;
      const float* qrow = qn + ((long)(b * SEQ + l0 + i)) * DMODEL + h * DHEAD;
      float4 a = *(const float4*)(qrow + lane * 4);
      for (int j = 0; j < 32; ++j) {
        float val = 0.f;
        if (j <= i) {
          float4 bb = *(const float4*)&Ks[j][lane * 4];
          float pd = a.x * bb.x + a.y * bb.y + a.z * bb.z + a.w * bb.w;
#pragma unroll
          for (int m = 1; m < 64; m <<= 1) pd += __shfl_xor(pd, m);
          val = pd;
        }
        if (lane == 0) attn_g[abase + i * 32 + j] = val;
      }
    }
  }
}

/* ---------- phase B: sequential scan. block per (b,h, 8-col group of DV).
   delta ALIASES u: each u element is read once (start of iter) by the same thread
   that later writes delta to the same address, same iteration, same block. ---------- */
__global__ __launch_bounds__(256) void phaseB(
    const float* __restrict__ qn, const float* __restrict__ kn,
    const float* __restrict__ u, const float* __restrict__ w,
    const float* __restrict__ attn_g, float* __restrict__ delta /* == u */) {
  __shared__ float S[256][8];
  __shared__ float Us[32][8];
  __shared__ float As[32][33];
  const int bid = blockIdx.x;
  const int g = bid & 31;
  const int bh = bid >> 5;
  const int b = bh >> 2;
  const int h = bh & 3;
  const int d0 = g * 8;
  const int t = threadIdx.x;
  const int io = t >> 3;
  const int dd = t & 7;
#pragma unroll
  for (int r = 0; r < 8; ++r) ((float*)S)[t + 256 * r] = 0.f;
  __syncthreads();
  for (int c = 0; c < NCHUNK; ++c) {
    const int l0 = c * 32;
    Us[io][dd] = u[((long)bh * SEQ + l0 + io) * DHEAD + d0 + dd];
    {
      long abase = ((long)bh * NCHUNK + c) * 1024;
#pragma unroll
      for (int r = 0; r < 4; ++r) {
        int idx = t + 256 * r;
        As[idx >> 5][idx & 31] = attn_g[abase + idx];
      }
    }
    __syncthreads();
    /* u2 = u - w @ S */
    float acc = 0.f;
    {
      const float* wrow = w + ((long)bh * SEQ + l0 + io) * DHEAD;
#pragma unroll 8
      for (int k4 = 0; k4 < 64; ++k4) {
        float4 w4 = *(const float4*)(wrow + k4 * 4);
        acc = fmaf(w4.x, S[k4 * 4 + 0][dd], acc);
        acc = fmaf(w4.y, S[k4 * 4 + 1][dd], acc);
        acc = fmaf(w4.z, S[k4 * 4 + 2][dd], acc);
        acc = fmaf(w4.w, S[k4 * 4 + 3][dd], acc);
      }
    }
    float u2v = Us[io][dd] - acc;
    Us[io][dd] = u2v;
    __syncthreads();
    /* o = q @ S + attn @ u2 ; write over the u slot read above */
    float oacc = 0.f;
    {
      const float* qrow = qn + ((long)(b * SEQ + l0 + io)) * DMODEL + h * DHEAD;
#pragma unroll 8
      for (int k4 = 0; k4 < 64; ++k4) {
        float4 q4 = *(const float4*)(qrow + k4 * 4);
        oacc = fmaf(q4.x, S[k4 * 4 + 0][dd], oacc);
        oacc = fmaf(q4.y, S[k4 * 4 + 1][dd], oacc);
        oacc = fmaf(q4.z, S[k4 * 4 + 2][dd], oacc);
        oacc = fmaf(q4.w, S[k4 * 4 + 3][dd], oacc);
      }
#pragma unroll
      for (int j = 0; j < 32; ++j) oacc = fmaf(As[io][j], Us[j][dd], oacc);
    }
    delta[((long)bh * SEQ + l0 + io) * DHEAD + d0 + dd] = oacc;
    __syncthreads();
    /* S += kn^T @ u2 ; thread owns S row k = t */
    {
      const int k = t;
      const float* kcol = kn + ((long)(b * SEQ + l0)) * DMODEL + h * DHEAD + k;
      float4 lo = *(float4*)&S[k][0];
      float4 hi = *(float4*)&S[k][4];
#pragma unroll 4
      for (int i = 0; i < 32; ++i) {
        float kv = kcol[(long)i * DMODEL];
        float4 ul = *(const float4*)&Us[i][0];
        float4 uh = *(const float4*)&Us[i][4];
        lo.x = fmaf(kv, ul.x, lo.x); lo.y = fmaf(kv, ul.y, lo.y);
        lo.z = fmaf(kv, ul.z, lo.z); lo.w = fmaf(kv, ul.w, lo.w);
        hi.x = fmaf(kv, uh.x, hi.x); hi.y = fmaf(kv, uh.y, hi.y);
        hi.z = fmaf(kv, uh.z, hi.z); hi.w = fmaf(kv, uh.w, hi.w);
      }
      *(float4*)&S[k][0] = lo;
      *(float4*)&S[k][4] = hi;
    }
    __syncthreads();
  }
}

/* ---------- FIR short(3)+long(31) causal depthwise convs on vh ---------- */
__global__ __launch_bounds__(256) void fir_kernel(
    const float* __restrict__ v, const float* __restrict__ fshort,
    const float* __restrict__ flong, float* __restrict__ fs, float* __restrict__ fl) {
  const int row = blockIdx.x;
  const int l = row & (SEQ - 1);
  const int t = threadIdx.x;
  const int cb = t * 4;
  float4 accl = make_float4(0, 0, 0, 0);
  float4 accs = make_float4(0, 0, 0, 0);
  for (int j = 0; j < 31; ++j) {
    int lr = l - 30 + j;
    if (lr < 0) continue;
    float4 xv = *(const float4*)(v + (long)(row - 30 + j) * DMODEL + cb);
    float w0 = flong[(cb + 0) * 31 + j];
    float w1 = flong[(cb + 1) * 31 + j];
    float w2 = flong[(cb + 2) * 31 + j];
    float w3 = flong[(cb + 3) * 31 + j];
    accl.x = fmaf(w0, xv.x, accl.x);
    accl.y = fmaf(w1, xv.y, accl.y);
    accl.z = fmaf(w2, xv.z, accl.z);
    accl.w = fmaf(w3, xv.w, accl.w);
    if (j >= 28) {
      int tp = j - 28;
      float s0 = fshort[(cb + 0) * 3 + tp];
      float s1 = fshort[(cb + 1) * 3 + tp];
      float s2 = fshort[(cb + 2) * 3 + tp];
      float s3 = fshort[(cb + 3) * 3 + tp];
      accs.x = fmaf(s0, xv.x, accs.x);
      accs.y = fmaf(s1, xv.y, accs.y);
      accs.z = fmaf(s2, xv.z, accs.z);
      accs.w = fmaf(s3, xv.w, accs.w);
    }
  }
  *(float4*)(fs + (long)row * DMODEL + cb) = accs;
  *(float4*)(fl + (long)row * DMODEL + cb) = accl;
}

/* ---------- stats + assemble router input. delta layout (B,H,L,DV). ---------- */
__global__ __launch_bounds__(256) void stats_router(
    const float* __restrict__ x, const float* __restrict__ fs,
    const float* __restrict__ fl, const float* __restrict__ dl, float* __restrict__ rin) {
  const int row = blockIdx.x;
  const int b = row >> 12;
  const int l = row & (SEQ - 1);
  const int t = threadIdx.x;
  float4 xv = *(const float4*)(x + (long)row * DMODEL + t * 4);
  *(float4*)(rin + (long)row * 1048 + t * 4) = xv;
  const int h = t >> 6;
  const int lane = t & 63;
  const long base = (long)row * DMODEL + h * DHEAD + lane * 4;
  const long dbase = ((long)(b * NH + h) * SEQ + l) * DHEAD + lane * 4;
  float4 a = *(const float4*)(fs + base);
  float4 bq = *(const float4*)(fl + base);
  float4 cq = *(const float4*)(dl + dbase);
  float s[6];
  s[0] = a.x + a.y + a.z + a.w;
  s[1] = a.x * a.x + a.y * a.y + a.z * a.z + a.w * a.w;
  s[2] = bq.x + bq.y + bq.z + bq.w;
  s[3] = bq.x * bq.x + bq.y * bq.y + bq.z * bq.z + bq.w * bq.w;
  s[4] = cq.x + cq.y + cq.z + cq.w;
  s[5] = cq.x * cq.x + cq.y * cq.y + cq.z * cq.z + cq.w * cq.w;
#pragma unroll
  for (int m = 1; m < 64; m <<= 1)
#pragma unroll
    for (int j = 0; j < 6; ++j) s[j] += __shfl_xor(s[j], m);
  if (lane == 0) {
    float* rb = rin + (long)row * 1048 + 1024;
    float m0 = s[0] * (1.f / 256.f);
    float m1 = s[2] * (1.f / 256.f);
    float m2 = s[4] * (1.f / 256.f);
    rb[h] = m0;
    rb[4 + h] = sqrtf(fmaxf(s[1] * (1.f / 256.f) - m0 * m0, 0.f));
    rb[8 + h] = m1;
    rb[12 + h] = sqrtf(fmaxf(s[3] * (1.f / 256.f) - m1 * m1, 0.f));
    rb[16 + h] = m2;
    rb[20 + h] = sqrtf(fmaxf(s[5] * (1.f / 256.f) - m2 * m2, 0.f));
  }
}

/* ---------- logits from bf16 hmid ; p = softmax(logits/tau)*0.925+0.025 ---------- */
__global__ __launch_bounds__(256) void router_logits(
    const __hip_bfloat16* __restrict__ hmid, const float* __restrict__ Wr2,
    const float* __restrict__ br2, const float* __restrict__ ltg, float* __restrict__ p) {
  const int row = blockIdx.x;
  const int t = threadIdx.x;
  float acc[12];
#pragma unroll
  for (int j = 0; j < 12; ++j) acc[j] = 0.f;
  const __hip_bfloat16* hr = hmid + (long)row * 2048;
  for (int k = t; k < 2048; k += 256) {
    float hv = __bfloat162float(hr[k]);
    const float* wr = Wr2 + k * 12;
#pragma unroll
    for (int j = 0; j < 12; ++j) acc[j] = fmaf(hv, wr[j], acc[j]);
  }
#pragma unroll
  for (int m = 1; m < 64; m <<= 1)
#pragma unroll
    for (int j = 0; j < 12; ++j) acc[j] += __shfl_xor(acc[j], m);
  __shared__ float red[4][12];
  if ((t & 63) == 0) {
    int wv = t >> 6;
#pragma unroll
    for (int j = 0; j < 12; ++j) red[wv][j] = acc[j];
  }
  __syncthreads();
  if (t < 4) {
    const int h = t;
    float l3[3];
#pragma unroll
    for (int j = 0; j < 3; ++j) {
      int col = h * 3 + j;
      l3[j] = red[0][col] + red[1][col] + red[2][col] + red[3][col] + br2[col];
    }
    float inv_tau = expf(-ltg[h >> 1]);
    float y0 = l3[0] * inv_tau, y1 = l3[1] * inv_tau, y2 = l3[2] * inv_tau;
    float mx = fmaxf(y0, fmaxf(y1, y2));
    float e0 = expf(y0 - mx), e1 = expf(y1 - mx), e2 = expf(y2 - mx);
    float inv = 1.f / (e0 + e1 + e2);
    p[(long)row * 12 + h * 3 + 0] = e0 * inv * 0.925f + 0.025f;
    p[(long)row * 12 + h * 3 + 1] = e1 * inv * 0.925f + 0.025f;
    p[(long)row * 12 + h * 3 + 2] = e2 * inv * 0.925f + 0.025f;
  }
}

/* ---------- mixture + identity path + RMS norm. delta layout (B,H,L,DV). ---------- */
__global__ __launch_bounds__(256) void omix(
    const float* __restrict__ fs, const float* __restrict__ fl,
    const float* __restrict__ dl, const float* __restrict__ vh,
    const float* __restrict__ p, const float* __restrict__ idsc,
    const float* __restrict__ onw, float* __restrict__ o) {
  const int row = blockIdx.x;
  const int b = row >> 12;
  const int l = row & (SEQ - 1);
  const int t = threadIdx.x;
  const int h = t >> 6;
  const int lane = t & 63;
  const long base = (long)row * DMODEL + h * DHEAD + lane * 4;
  const long dbase = ((long)(b * NH + h) * SEQ + l) * DHEAD + lane * 4;
  float p0 = p[(long)row * 12 + h * 3 + 0];
  float p1 = p[(long)row * 12 + h * 3 + 1];
  float p2 = p[(long)row * 12 + h * 3 + 2];
  float idv = idsc[(long)row * NH + h];
  float4 a = *(const float4*)(fs + base);
  float4 bq = *(const float4*)(fl + base);
  float4 cq = *(const float4*)(dl + dbase);
  float4 vv = *(const float4*)(vh + base);
  float4 ov;
  ov.x = p0 * a.x + p1 * bq.x + p2 * cq.x + idv * vv.x;
  ov.y = p0 * a.y + p1 * bq.y + p2 * cq.y + idv * vv.y;
  ov.z = p0 * a.z + p1 * bq.z + p2 * cq.z + idv * vv.z;
  ov.w = p0 * a.w + p1 * bq.w + p2 * cq.w + idv * vv.w;
  float ss = ov.x * ov.x + ov.y * ov.y + ov.z * ov.z + ov.w * ov.w;
#pragma unroll
  for (int m = 1; m < 64; m <<= 1) ss += __shfl_xor(ss, m);
  float rms = rsqrtf(ss * (1.f / 256.f) + 1e-5f);
  float4 wn = *(const float4*)(onw + lane * 4);
  ov.x *= rms * wn.x;
  ov.y *= rms * wn.y;
  ov.z *= rms * wn.z;
  ov.w *= rms * wn.w;
  *(float4*)(o + base) = ov;
}

extern "C" void kernel_launch(void* const* d_in, const int* in_sizes, int n_in,
                              void* d_out, int out_size, void* d_ws, size_t ws_size,
                              hipStream_t stream) {
  const float* x = (const float*)d_in[0];
  const float* Wq = (const float*)d_in[1];
  const float* Wk = (const float*)d_in[2];
  const float* Wv = (const float*)d_in[3];
  const float* Wb = (const float*)d_in[4];
  const float* conv_q = (const float*)d_in[5];
  const float* conv_k = (const float*)d_in[6];
  const float* conv_v = (const float*)d_in[7];
  const float* fir_s = (const float*)d_in[8];
  const float* fir_l = (const float*)d_in[9];
  const float* alpha_id = (const float*)d_in[10];
  const float* Wid = (const float*)d_in[11];
  const float* bidp = (const float*)d_in[12];
  const float* Wr1 = (const float*)d_in[13];
  const float* br1 = (const float*)d_in[14];
  const float* Wr2 = (const float*)d_in[15];
  const float* br2 = (const float*)d_in[16];
  const float* ltg = (const float*)d_in[17];
  const float* onw = (const float*)d_in[19];
  const float* Wo = (const float*)d_in[20];

  /* ---- workspace layout (f32 elements), peak ~197 MB ----
     P   [0,        8388608)  pre scratch; later hmid (bf16, 8192x2048 = 32MB)
     U   [8388608, 16777216)  u; phaseB overwrites in place with delta (B,H,L,DV)
     W   [16777216,25165824)  w; later rin (8192x1048, spills into ATT); later omixbuf
     ATT [25165824,26214400)  attn (8,128,32,32)
     Q   [26214400,34603008)  q post-conv/l2norm; later fs
     K   [34603008,42991616)  k post-conv/l2norm; later fl
     V   [42991616,51380224)  v post-conv (alive to the end)
     BETA[51380224,51412992)  IDSC[51412992,51445760)  PMIX[51445760,51544064) */
  float* ws = (float*)d_ws;
  float* pre = ws + 0;
  float* ubuf = ws + 8388608;
  float* wbuf = ws + 16777216;
  float* attnbuf = ws + 25165824;
  float* qbuf = ws + 26214400;
  float* kbuf = ws + 34603008;
  float* vbuf = ws + 42991616;
  float* betabuf = ws + 51380224;
  float* idscbuf = ws + 51412992;
  float* pbuf = ws + 51445760;
  float* deltabuf = ubuf;                       /* alias: phaseB in-place */
  float* rin = wbuf;                            /* 8.59M floats over W+ATT */
  float* omixbuf = wbuf;                        /* after rin is dead */
  __hip_bfloat16* hmid = (__hip_bfloat16*)pre;  /* 16.78M bf16 over P */
  float* fsb = qbuf;                            /* fir outputs over dead q,k */
  float* flb = kbuf;

  dim3 blk(256);
  /* 1) projections + causal dwconv + silu (pre scratch reused per plane) */
  gemm_t<0, false><<<dim3(8, 64), blk, 0, stream>>>(x, Wq, nullptr, pre, ROWS, 1024, 1024);
  conv_silu<<<dim3(ROWS), blk, 0, stream>>>(pre, conv_q, qbuf);
  gemm_t<0, false><<<dim3(8, 64), blk, 0, stream>>>(x, Wk, nullptr, pre, ROWS, 1024, 1024);
  conv_silu<<<dim3(ROWS), blk, 0, stream>>>(pre, conv_k, kbuf);
  gemm_t<0, false><<<dim3(8, 64), blk, 0, stream>>>(x, Wv, nullptr, pre, ROWS, 1024, 1024);
  conv_silu<<<dim3(ROWS), blk, 0, stream>>>(pre, conv_v, vbuf);
  /* 2) beta / id_scale */
  rowdot8<<<dim3(ROWS), blk, 0, stream>>>(x, Wb, Wid, alpha_id, bidp, betabuf, idscbuf);
  /* 3) l2norm q,k in place */
  l2norm_qk<<<dim3(ROWS), blk, 0, stream>>>(qbuf, kbuf);
  /* 4) delta rule */
  phaseA<<<dim3(BATCH * NH * NCHUNK), blk, 0, stream>>>(qbuf, kbuf, vbuf, betabuf, ubuf, wbuf, attnbuf);
  phaseB<<<dim3(BATCH * NH * 32), blk, 0, stream>>>(qbuf, kbuf, ubuf, wbuf, attnbuf, deltabuf);
  /* 5) FIR convs into dead q,k regions */
  fir_kernel<<<dim3(ROWS), blk, 0, stream>>>(vbuf, fir_s, fir_l, fsb, flb);
  /* 6) stats + router input over dead w/attn */
  stats_router<<<dim3(ROWS), blk, 0, stream>>>(x, fsb, flb, deltabuf, rin);
  /* 7) router MLP layer 1 (gelu fused, bf16 out over dead pre) */
  gemm_t<1, true><<<dim3(16, 64), blk, 0, stream>>>(rin, Wr1, br1, hmid, ROWS, 2048, 1048);
  /* 8) router logits + softmax */
  router_logits<<<dim3(ROWS), blk, 0, stream>>>(hmid, Wr2, br2, ltg, pbuf);
  /* 9) mixture + id path + RMS norm (omixbuf over dead rin) */
  omix<<<dim3(ROWS), blk, 0, stream>>>(fsb, flb, deltabuf, vbuf, pbuf, idscbuf, onw, omixbuf);
  /* 10) output projection */
  gemm_t<0, false><<<dim3(8, 64), blk, 0, stream>>>(omixbuf, Wo, nullptr, d_out, ROWS, 1024, 1024);
}

// Round 3
// 2673.341 us; speedup vs baseline: 1.4953x; 1.4953x over previous
//
#include <hip/hip_runtime.h>
#include <hip/hip_bf16.h>
#include <math.h>

#define BATCH 2
#define SEQ 4096
#define DMODEL 1024
#define NH 4
#define DHEAD 256
#define NCHUNK 128
#define ROWS (BATCH * SEQ) /* 8192 */

typedef short s8v __attribute__((ext_vector_type(8)));   /* 8 bf16 in 4 VGPRs */
typedef float f4v __attribute__((ext_vector_type(4)));

__device__ __forceinline__ float sigm(float x) { return 1.0f / (1.0f + expf(-x)); }
__device__ __forceinline__ float siluf(float x) { return x / (1.0f + expf(-x)); }

/* ---------- cast f32 -> bf16, n multiple of 1024, grid = n/1024 ---------- */
__global__ __launch_bounds__(256) void cast_bf16(
    const float* __restrict__ in, __hip_bfloat16* __restrict__ out) {
  long i = ((long)blockIdx.x * 256 + threadIdx.x) * 4;
  float4 v = *(const float4*)(in + i);
  __hip_bfloat16 tmp[4] = {__float2bfloat16(v.x), __float2bfloat16(v.y),
                           __float2bfloat16(v.z), __float2bfloat16(v.w)};
  *(ushort4*)(out + i) = *(ushort4*)tmp;
}

/* ---------- transpose K x N f32 -> N x Ks bf16 (zero-pad rows K..Ks) ----------
   grid (N/32, Ks/32), 256 threads */
__global__ __launch_bounds__(256) void transpose_cast(
    const float* __restrict__ W, __hip_bfloat16* __restrict__ Wt,
    int K, int N, int Ks) {
  __shared__ float tile[32][33];
  const int t = threadIdx.x;
  const int tx = t & 31, ty = t >> 5; /* ty 0..7 */
  const int kb = blockIdx.y * 32, nb = blockIdx.x * 32;
#pragma unroll
  for (int r = 0; r < 4; ++r) {
    int kk = kb + ty + 8 * r;
    tile[ty + 8 * r][tx] = (kk < K) ? W[(long)kk * N + nb + tx] : 0.f;
  }
  __syncthreads();
#pragma unroll
  for (int r = 0; r < 4; ++r) {
    Wt[(long)(nb + ty + 8 * r) * Ks + kb + tx] = __float2bfloat16(tile[tx][ty + 8 * r]);
  }
}

/* ---------------- bf16 MFMA GEMM: C = A(MxKs) * Bt(NxKs)^T ----------------
   A row-major bf16 (stride Ks), Bt row-major bf16 (stride Ks).
   128x128 tile, 256 threads = 4 waves (2x2 quadrants of 64x64), K-step 32.
   ACT=1: bias+gelu. BF16OUT: store bf16 else f32. Ks%32==0, M%128==0, N%128==0. */
template <int ACT, bool BF16OUT>
__global__ __launch_bounds__(256) void gemm_bf16(
    const __hip_bfloat16* __restrict__ A, const __hip_bfloat16* __restrict__ Bt,
    const float* __restrict__ bias, void* __restrict__ Cv,
    int M, int N, int Ks) {
  __shared__ short As[128 * 32];
  __shared__ short Bs[128 * 32];
  const int t = threadIdx.x;
  const int wv = t >> 6;
  const int lane = t & 63;
  const int row0 = blockIdx.y * 128, col0 = blockIdx.x * 128;
  const int mq = (wv >> 1) * 64, nq = (wv & 1) * 64;
  const int ln15 = lane & 15;
  const int kq = (lane >> 4) * 8; /* k offset of this lane's fragment */
  /* staging: thread t covers rows sr and sr+64, 8 bf16 at col sc */
  const int sr = t >> 2;
  const int sc = (t & 3) * 8;
  const short* Ag = (const short*)A + (long)(row0 + sr) * Ks + sc;
  const short* Bg = (const short*)Bt + (long)(col0 + sr) * Ks + sc;
  const long rstep = (long)64 * Ks;

  f4v acc[4][4];
#pragma unroll
  for (int i = 0; i < 4; ++i)
#pragma unroll
    for (int j = 0; j < 4; ++j) acc[i][j] = (f4v){0.f, 0.f, 0.f, 0.f};

  uint4 a0 = *(const uint4*)(Ag);
  uint4 a1 = *(const uint4*)(Ag + rstep);
  uint4 b0 = *(const uint4*)(Bg);
  uint4 b1 = *(const uint4*)(Bg + rstep);
  for (int k0 = 0; k0 < Ks; k0 += 32) {
    __syncthreads(); /* previous iter's LDS reads done */
    *(uint4*)&As[sr * 32 + sc] = a0;
    *(uint4*)&As[(sr + 64) * 32 + sc] = a1;
    *(uint4*)&Bs[sr * 32 + sc] = b0;
    *(uint4*)&Bs[(sr + 64) * 32 + sc] = b1;
    __syncthreads();
    if (k0 + 32 < Ks) { /* prefetch next tile, overlaps MFMA below */
      a0 = *(const uint4*)(Ag + k0 + 32);
      a1 = *(const uint4*)(Ag + rstep + k0 + 32);
      b0 = *(const uint4*)(Bg + k0 + 32);
      b1 = *(const uint4*)(Bg + rstep + k0 + 32);
    }
    s8v af[4], bf[4];
#pragma unroll
    for (int mt = 0; mt < 4; ++mt)
      af[mt] = *(const s8v*)&As[(mq + mt * 16 + ln15) * 32 + kq];
#pragma unroll
    for (int nt = 0; nt < 4; ++nt)
      bf[nt] = *(const s8v*)&Bs[(nq + nt * 16 + ln15) * 32 + kq];
#pragma unroll
    for (int mt = 0; mt < 4; ++mt)
#pragma unroll
      for (int nt = 0; nt < 4; ++nt)
        acc[mt][nt] = __builtin_amdgcn_mfma_f32_16x16x32_bf16(af[mt], bf[nt], acc[mt][nt], 0, 0, 0);
  }
  /* epilogue: C/D layout col=lane&15, row=(lane>>4)*4+reg */
  const int rbase = (lane >> 4) * 4;
#pragma unroll
  for (int mt = 0; mt < 4; ++mt) {
#pragma unroll
    for (int nt = 0; nt < 4; ++nt) {
      int gcol = col0 + nq + nt * 16 + ln15;
#pragma unroll
      for (int r = 0; r < 4; ++r) {
        int grow = row0 + mq + mt * 16 + rbase + r;
        float v = acc[mt][nt][r];
        if (ACT == 1) {
          v += bias[gcol];
          v = 0.5f * v * (1.0f + erff(v * 0.70710678118654752f));
        }
        if (BF16OUT) {
          ((__hip_bfloat16*)Cv)[(long)grow * N + gcol] = __float2bfloat16(v);
        } else {
          ((float*)Cv)[(long)grow * N + gcol] = v;
        }
      }
    }
  }
}

/* ---------- beta = sigmoid(x@Wb), idsc = 0.06 + sig(alpha)*sig(x@Wid + bid) ---------- */
__global__ __launch_bounds__(256) void rowdot8(
    const float* __restrict__ x, const float* __restrict__ Wb,
    const float* __restrict__ Wid, const float* __restrict__ alpha_id,
    const float* __restrict__ bidp, float* __restrict__ beta, float* __restrict__ idsc) {
  const int row = blockIdx.x;
  const int t = threadIdx.x;
  const float* xr = x + (long)row * DMODEL;
  float ab[4] = {0, 0, 0, 0}, ai[4] = {0, 0, 0, 0};
  for (int k = t; k < DMODEL; k += 256) {
    float xv = xr[k];
    float4 wb = *(const float4*)(Wb + k * 4);
    float4 wi = *(const float4*)(Wid + k * 4);
    ab[0] = fmaf(xv, wb.x, ab[0]); ab[1] = fmaf(xv, wb.y, ab[1]);
    ab[2] = fmaf(xv, wb.z, ab[2]); ab[3] = fmaf(xv, wb.w, ab[3]);
    ai[0] = fmaf(xv, wi.x, ai[0]); ai[1] = fmaf(xv, wi.y, ai[1]);
    ai[2] = fmaf(xv, wi.z, ai[2]); ai[3] = fmaf(xv, wi.w, ai[3]);
  }
#pragma unroll
  for (int m = 1; m < 64; m <<= 1) {
#pragma unroll
    for (int hh = 0; hh < 4; ++hh) {
      ab[hh] += __shfl_xor(ab[hh], m);
      ai[hh] += __shfl_xor(ai[hh], m);
    }
  }
  __shared__ float red[4][8];
  if ((t & 63) == 0) {
    int wv = t >> 6;
#pragma unroll
    for (int hh = 0; hh < 4; ++hh) {
      red[wv][hh] = ab[hh];
      red[wv][4 + hh] = ai[hh];
    }
  }
  __syncthreads();
  if (t < 8) {
    float s = red[0][t] + red[1][t] + red[2][t] + red[3][t];
    if (t < 4) {
      beta[(long)row * NH + t] = sigm(s);
    } else {
      int hh = t - 4;
      idsc[(long)row * NH + hh] = 0.06f + sigm(alpha_id[hh]) * sigm(s + bidp[hh]);
    }
  }
}

/* ---------- causal depthwise conv (K=4) + silu, single plane ---------- */
__global__ __launch_bounds__(256) void conv_silu(
    const float* __restrict__ pre, const float* __restrict__ cw, float* __restrict__ out) {
  const int row = blockIdx.x;
  const int l = row & (SEQ - 1);
  const int t = threadIdx.x;
  const int cb = t * 4;
  float wts[4][4];
#pragma unroll
  for (int cc = 0; cc < 4; ++cc) {
    float4 w4 = *(const float4*)(cw + (cb + cc) * 4);
    wts[cc][0] = w4.x; wts[cc][1] = w4.y; wts[cc][2] = w4.z; wts[cc][3] = w4.w;
  }
  float acc[4] = {0, 0, 0, 0};
#pragma unroll
  for (int tap = 0; tap < 4; ++tap) {
    int lr = l - 3 + tap;
    if (lr >= 0) {
      float4 xv = *(const float4*)(pre + (long)(row - 3 + tap) * DMODEL + cb);
      acc[0] = fmaf(wts[0][tap], xv.x, acc[0]);
      acc[1] = fmaf(wts[1][tap], xv.y, acc[1]);
      acc[2] = fmaf(wts[2][tap], xv.z, acc[2]);
      acc[3] = fmaf(wts[3][tap], xv.w, acc[3]);
    }
  }
  float4 ov = make_float4(siluf(acc[0]), siluf(acc[1]), siluf(acc[2]), siluf(acc[3]));
  *(float4*)(out + (long)row * DMODEL + cb) = ov;
}

/* ---------- in-place l2norm of q,k per (row, head); one wave per unit ---------- */
__global__ __launch_bounds__(256) void l2norm_qk(float* __restrict__ q, float* __restrict__ k) {
  const int t = threadIdx.x;
  const int unit = blockIdx.x * 4 + (t >> 6);
  const int lane = t & 63;
  const int row = unit >> 2;
  const int h = unit & 3;
  const long base = (long)row * DMODEL + h * DHEAD + lane * 4;
  float4 q4 = *(const float4*)(q + base);
  float4 k4 = *(const float4*)(k + base);
  float sq = q4.x * q4.x + q4.y * q4.y + q4.z * q4.z + q4.w * q4.w;
  float sk = k4.x * k4.x + k4.y * k4.y + k4.z * k4.z + k4.w * k4.w;
#pragma unroll
  for (int m = 1; m < 64; m <<= 1) {
    sq += __shfl_xor(sq, m);
    sk += __shfl_xor(sk, m);
  }
  float rq = rsqrtf(sq + 1e-6f);
  float rk = rsqrtf(sk + 1e-6f);
  q4.x *= rq; q4.y *= rq; q4.z *= rq; q4.w *= rq;
  k4.x *= rk; k4.y *= rk; k4.z *= rk; k4.w *= rk;
  *(float4*)(q + base) = q4;
  *(float4*)(k + base) = k4;
}

/* ---------- phase A: per-chunk T solve, u=T'v, w=T'k, attn. block per (b,h,chunk) ---------- */
__global__ __launch_bounds__(256) void phaseA(
    const float* __restrict__ qn, const float* __restrict__ kn, const float* __restrict__ v,
    const float* __restrict__ beta, float* __restrict__ u, float* __restrict__ w,
    float* __restrict__ attn_g) {
  __shared__ float Ks[32][256];
  __shared__ float T[32][33];
  __shared__ float bet[32];
  const int bid = blockIdx.x;
  const int c = bid & (NCHUNK - 1);
  const int h = (bid >> 7) & 3;
  const int b = bid >> 9;
  const int bh = b * NH + h;
  const int l0 = c * 32;
  const int t = threadIdx.x;
  const int wv = t >> 6;
  const int lane = t & 63;

#pragma unroll
  for (int r = 0; r < 8; ++r) {
    int idx = t + 256 * r;
    int i = idx >> 6;
    int f = (idx & 63) * 4;
    long gq = ((long)(b * SEQ + l0 + i)) * DMODEL + h * DHEAD + f;
    *(float4*)&Ks[i][f] = *(const float4*)(kn + gq);
  }
  if (t < 32) bet[t] = beta[(long)(b * SEQ + l0 + t) * NH + h];
  __syncthreads();

  {
#pragma unroll
    for (int ii = 0; ii < 8; ++ii) {
      const int i = wv * 8 + ii;
      float4 a = *(const float4*)&Ks[i][lane * 4];
      float nbi = -bet[i];
      for (int j = 0; j < 32; ++j) {
        float val = 0.f;
        if (j < i) {
          float4 bb = *(const float4*)&Ks[j][lane * 4];
          float pd = a.x * bb.x + a.y * bb.y + a.z * bb.z + a.w * bb.w;
#pragma unroll
          for (int m = 1; m < 64; m <<= 1) pd += __shfl_xor(pd, m);
          val = nbi * pd;
        }
        if (lane == 0) T[i][j] = val;
      }
    }
  }
  __syncthreads();

  if (t < 32) {
    const int l = t;
    for (int i = 1; i < 32; ++i) {
      float s = 0.f;
      for (int j = 0; j < i; ++j) s = fmaf(T[i][j], T[j][l], s);
      T[i][l] += s;
    }
    for (int i = 0; i < 32; ++i) {
      float val = T[i][l] + (i == l ? 1.f : 0.f);
      T[i][l] = val * bet[l];
    }
  }
  __syncthreads();

  {
    const int d = t;
    float acc[32];
#pragma unroll
    for (int i = 0; i < 32; ++i) acc[i] = 0.f;
    for (int j = 0; j < 32; ++j) {
      float vv = v[((long)(b * SEQ + l0 + j)) * DMODEL + h * DHEAD + d];
#pragma unroll
      for (int i = 0; i < 32; ++i) acc[i] = fmaf(T[i][j], vv, acc[i]);
    }
    long ubase = ((long)bh * SEQ + l0) * DHEAD + d;
#pragma unroll
    for (int i = 0; i < 32; ++i) u[ubase + (long)i * DHEAD] = acc[i];
#pragma unroll
    for (int i = 0; i < 32; ++i) acc[i] = 0.f;
    for (int j = 0; j < 32; ++j) {
      float kv = Ks[j][d];
#pragma unroll
      for (int i = 0; i < 32; ++i) acc[i] = fmaf(T[i][j], kv, acc[i]);
    }
#pragma unroll
    for (int i = 0; i < 32; ++i) w[ubase + (long)i * DHEAD] = acc[i];
  }
  __syncthreads();

  {
    long abase = ((long)bh * NCHUNK + c) * 1024;
#pragma unroll
    for (int ii = 0; ii < 8; ++ii) {
      const int i = wv * 8 + ii;
      const float* qrow = qn + ((long)(b * SEQ + l0 + i)) * DMODEL + h * DHEAD;
      float4 a = *(const float4*)(qrow + lane * 4);
      for (int j = 0; j < 32; ++j) {
        float val = 0.f;
        if (j <= i) {
          float4 bb = *(const float4*)&Ks[j][lane * 4];
          float pd = a.x * bb.x + a.y * bb.y + a.z * bb.z + a.w * bb.w;
#pragma unroll
          for (int m = 1; m < 64; m <<= 1) pd += __shfl_xor(pd, m);
          val = pd;
        }
        if (lane == 0) attn_g[abase + i * 32 + j] = val;
      }
    }
  }
}

/* ---------- phase B v2: 512 blocks x 128 threads; (b,h) x 64 DV-groups of 4.
   St transposed [4][257], merged w@S + q@S pass, 2 barriers/chunk.
   delta aliases u (each u element read once by the thread that overwrites it). ---------- */
__global__ __launch_bounds__(128) void phaseB(
    const float* __restrict__ qn, const float* __restrict__ kn,
    const float* __restrict__ u, const float* __restrict__ w,
    const float* __restrict__ attn_g, float* __restrict__ delta /* == u */) {
  __shared__ float St[4][257];
  __shared__ float Us[32][4];
  __shared__ float As[32][33];
  const int bid = blockIdx.x;
  const int g = bid & 63;
  const int bh = bid >> 6;
  const int b = bh >> 2;
  const int h = bh & 3;
  const int d0 = g * 4;
  const int t = threadIdx.x;
  const int io = t >> 2;
  const int dd = t & 3;
  for (int i = t; i < 4 * 257; i += 128) ((float*)St)[i] = 0.f;
  __syncthreads();
  const float* Sd = &St[dd][0];
  for (int c = 0; c < NCHUNK; ++c) {
    const int l0 = c * 32;
    /* own u element + attn staging (no barrier needed: As reads of prev iter ended at tail sync) */
    float uval = u[((long)bh * SEQ + l0 + io) * DHEAD + d0 + dd];
    {
      long abase = ((long)bh * NCHUNK + c) * 1024;
#pragma unroll
      for (int r = 0; r < 8; ++r) {
        int idx = t + 128 * r;
        As[idx >> 5][idx & 31] = attn_g[abase + idx];
      }
    }
    /* merged pass: aw = w@S, aq = q@S (single sweep of St) */
    float aw0 = 0.f, aw1 = 0.f, aw2 = 0.f, aw3 = 0.f;
    float aq0 = 0.f, aq1 = 0.f, aq2 = 0.f, aq3 = 0.f;
    {
      const float* wrow = w + ((long)bh * SEQ + l0 + io) * DHEAD;
      const float* qrow = qn + ((long)(b * SEQ + l0 + io)) * DMODEL + h * DHEAD;
#pragma unroll 8
      for (int k4 = 0; k4 < 64; ++k4) {
        float4 w4 = *(const float4*)(wrow + k4 * 4);
        float4 q4 = *(const float4*)(qrow + k4 * 4);
        float s0 = Sd[k4 * 4 + 0], s1 = Sd[k4 * 4 + 1];
        float s2 = Sd[k4 * 4 + 2], s3 = Sd[k4 * 4 + 3];
        aw0 = fmaf(w4.x, s0, aw0); aw1 = fmaf(w4.y, s1, aw1);
        aw2 = fmaf(w4.z, s2, aw2); aw3 = fmaf(w4.w, s3, aw3);
        aq0 = fmaf(q4.x, s0, aq0); aq1 = fmaf(q4.y, s1, aq1);
        aq2 = fmaf(q4.z, s2, aq2); aq3 = fmaf(q4.w, s3, aq3);
      }
    }
    float u2v = uval - (aw0 + aw1 + aw2 + aw3);
    Us[io][dd] = u2v;
    float oq = aq0 + aq1 + aq2 + aq3;
    __syncthreads(); /* (1) Us + As visible */
    /* o = q@S + attn@u2 */
    {
      float oacc = oq;
#pragma unroll
      for (int j = 0; j < 32; ++j) oacc = fmaf(As[io][j], Us[j][dd], oacc);
      delta[((long)bh * SEQ + l0 + io) * DHEAD + d0 + dd] = oacc;
    }
    /* S += kn^T @ u2 ; thread owns state rows t and t+128 */
    {
#pragma unroll
      for (int half = 0; half < 2; ++half) {
        const int kk = t + half * 128;
        const float* kcol = kn + ((long)(b * SEQ + l0)) * DMODEL + h * DHEAD + kk;
        float s0 = St[0][kk], s1 = St[1][kk], s2 = St[2][kk], s3 = St[3][kk];
#pragma unroll 8
        for (int i = 0; i < 32; ++i) {
          float kv = kcol[(long)i * DMODEL];
          float4 uu = *(const float4*)&Us[i][0];
          s0 = fmaf(kv, uu.x, s0);
          s1 = fmaf(kv, uu.y, s1);
          s2 = fmaf(kv, uu.z, s2);
          s3 = fmaf(kv, uu.w, s3);
        }
        St[0][kk] = s0; St[1][kk] = s1; St[2][kk] = s2; St[3][kk] = s3;
      }
    }
    __syncthreads(); /* (2) St/Us/As stable for next iter */
  }
}

/* ---------- FIR short(3)+long(31) causal depthwise convs on vh ---------- */
__global__ __launch_bounds__(256) void fir_kernel(
    const float* __restrict__ v, const float* __restrict__ fshort,
    const float* __restrict__ flong, float* __restrict__ fs, float* __restrict__ fl) {
  const int row = blockIdx.x;
  const int l = row & (SEQ - 1);
  const int t = threadIdx.x;
  const int cb = t * 4;
  float4 accl = make_float4(0, 0, 0, 0);
  float4 accs = make_float4(0, 0, 0, 0);
  for (int j = 0; j < 31; ++j) {
    int lr = l - 30 + j;
    if (lr < 0) continue;
    float4 xv = *(const float4*)(v + (long)(row - 30 + j) * DMODEL + cb);
    float w0 = flong[(cb + 0) * 31 + j];
    float w1 = flong[(cb + 1) * 31 + j];
    float w2 = flong[(cb + 2) * 31 + j];
    float w3 = flong[(cb + 3) * 31 + j];
    accl.x = fmaf(w0, xv.x, accl.x);
    accl.y = fmaf(w1, xv.y, accl.y);
    accl.z = fmaf(w2, xv.z, accl.z);
    accl.w = fmaf(w3, xv.w, accl.w);
    if (j >= 28) {
      int tp = j - 28;
      float s0 = fshort[(cb + 0) * 3 + tp];
      float s1 = fshort[(cb + 1) * 3 + tp];
      float s2 = fshort[(cb + 2) * 3 + tp];
      float s3 = fshort[(cb + 3) * 3 + tp];
      accs.x = fmaf(s0, xv.x, accs.x);
      accs.y = fmaf(s1, xv.y, accs.y);
      accs.z = fmaf(s2, xv.z, accs.z);
      accs.w = fmaf(s3, xv.w, accs.w);
    }
  }
  *(float4*)(fs + (long)row * DMODEL + cb) = accs;
  *(float4*)(fl + (long)row * DMODEL + cb) = accl;
}

/* ---------- stats + assemble router input as bf16 (stride 1056, zero pad) ---------- */
__global__ __launch_bounds__(256) void stats_router(
    const float* __restrict__ x, const float* __restrict__ fs,
    const float* __restrict__ fl, const float* __restrict__ dl,
    __hip_bfloat16* __restrict__ rinb) {
  const int row = blockIdx.x;
  const int b = row >> 12;
  const int l = row & (SEQ - 1);
  const int t = threadIdx.x;
  float4 xv = *(const float4*)(x + (long)row * DMODEL + t * 4);
  {
    __hip_bfloat16 tmp[4] = {__float2bfloat16(xv.x), __float2bfloat16(xv.y),
                             __float2bfloat16(xv.z), __float2bfloat16(xv.w)};
    *(ushort4*)(rinb + (long)row * 1056 + t * 4) = *(ushort4*)tmp;
  }
  if (t < 8) rinb[(long)row * 1056 + 1048 + t] = __float2bfloat16(0.f);
  const int h = t >> 6;
  const int lane = t & 63;
  const long base = (long)row * DMODEL + h * DHEAD + lane * 4;
  const long dbase = ((long)(b * NH + h) * SEQ + l) * DHEAD + lane * 4;
  float4 a = *(const float4*)(fs + base);
  float4 bq = *(const float4*)(fl + base);
  float4 cq = *(const float4*)(dl + dbase);
  float s[6];
  s[0] = a.x + a.y + a.z + a.w;
  s[1] = a.x * a.x + a.y * a.y + a.z * a.z + a.w * a.w;
  s[2] = bq.x + bq.y + bq.z + bq.w;
  s[3] = bq.x * bq.x + bq.y * bq.y + bq.z * bq.z + bq.w * bq.w;
  s[4] = cq.x + cq.y + cq.z + cq.w;
  s[5] = cq.x * cq.x + cq.y * cq.y + cq.z * cq.z + cq.w * cq.w;
#pragma unroll
  for (int m = 1; m < 64; m <<= 1)
#pragma unroll
    for (int j = 0; j < 6; ++j) s[j] += __shfl_xor(s[j], m);
  if (lane == 0) {
    __hip_bfloat16* rb = rinb + (long)row * 1056 + 1024;
    float m0 = s[0] * (1.f / 256.f);
    float m1 = s[2] * (1.f / 256.f);
    float m2 = s[4] * (1.f / 256.f);
    rb[h] = __float2bfloat16(m0);
    rb[4 + h] = __float2bfloat16(sqrtf(fmaxf(s[1] * (1.f / 256.f) - m0 * m0, 0.f)));
    rb[8 + h] = __float2bfloat16(m1);
    rb[12 + h] = __float2bfloat16(sqrtf(fmaxf(s[3] * (1.f / 256.f) - m1 * m1, 0.f)));
    rb[16 + h] = __float2bfloat16(m2);
    rb[20 + h] = __float2bfloat16(sqrtf(fmaxf(s[5] * (1.f / 256.f) - m2 * m2, 0.f)));
  }
}

/* ---------- logits from bf16 hmid ; p = softmax(logits/tau)*0.925+0.025 ---------- */
__global__ __launch_bounds__(256) void router_logits(
    const __hip_bfloat16* __restrict__ hmid, const float* __restrict__ Wr2,
    const float* __restrict__ br2, const float* __restrict__ ltg, float* __restrict__ p) {
  const int row = blockIdx.x;
  const int t = threadIdx.x;
  float acc[12];
#pragma unroll
  for (int j = 0; j < 12; ++j) acc[j] = 0.f;
  const __hip_bfloat16* hr = hmid + (long)row * 2048;
  for (int k = t; k < 2048; k += 256) {
    float hv = __bfloat162float(hr[k]);
    const float* wr = Wr2 + k * 12;
#pragma unroll
    for (int j = 0; j < 12; ++j) acc[j] = fmaf(hv, wr[j], acc[j]);
  }
#pragma unroll
  for (int m = 1; m < 64; m <<= 1)
#pragma unroll
    for (int j = 0; j < 12; ++j) acc[j] += __shfl_xor(acc[j], m);
  __shared__ float red[4][12];
  if ((t & 63) == 0) {
    int wv = t >> 6;
#pragma unroll
    for (int j = 0; j < 12; ++j) red[wv][j] = acc[j];
  }
  __syncthreads();
  if (t < 4) {
    const int h = t;
    float l3[3];
#pragma unroll
    for (int j = 0; j < 3; ++j) {
      int col = h * 3 + j;
      l3[j] = red[0][col] + red[1][col] + red[2][col] + red[3][col] + br2[col];
    }
    float inv_tau = expf(-ltg[h >> 1]);
    float y0 = l3[0] * inv_tau, y1 = l3[1] * inv_tau, y2 = l3[2] * inv_tau;
    float mx = fmaxf(y0, fmaxf(y1, y2));
    float e0 = expf(y0 - mx), e1 = expf(y1 - mx), e2 = expf(y2 - mx);
    float inv = 1.f / (e0 + e1 + e2);
    p[(long)row * 12 + h * 3 + 0] = e0 * inv * 0.925f + 0.025f;
    p[(long)row * 12 + h * 3 + 1] = e1 * inv * 0.925f + 0.025f;
    p[(long)row * 12 + h * 3 + 2] = e2 * inv * 0.925f + 0.025f;
  }
}

/* ---------- mixture + identity + RMS norm -> bf16 out. delta layout (B,H,L,DV). ---------- */
__global__ __launch_bounds__(256) void omix(
    const float* __restrict__ fs, const float* __restrict__ fl,
    const float* __restrict__ dl, const float* __restrict__ vh,
    const float* __restrict__ p, const float* __restrict__ idsc,
    const float* __restrict__ onw, __hip_bfloat16* __restrict__ o) {
  const int row = blockIdx.x;
  const int b = row >> 12;
  const int l = row & (SEQ - 1);
  const int t = threadIdx.x;
  const int h = t >> 6;
  const int lane = t & 63;
  const long base = (long)row * DMODEL + h * DHEAD + lane * 4;
  const long dbase = ((long)(b * NH + h) * SEQ + l) * DHEAD + lane * 4;
  float p0 = p[(long)row * 12 + h * 3 + 0];
  float p1 = p[(long)row * 12 + h * 3 + 1];
  float p2 = p[(long)row * 12 + h * 3 + 2];
  float idv = idsc[(long)row * NH + h];
  float4 a = *(const float4*)(fs + base);
  float4 bq = *(const float4*)(fl + base);
  float4 cq = *(const float4*)(dl + dbase);
  float4 vv = *(const float4*)(vh + base);
  float4 ov;
  ov.x = p0 * a.x + p1 * bq.x + p2 * cq.x + idv * vv.x;
  ov.y = p0 * a.y + p1 * bq.y + p2 * cq.y + idv * vv.y;
  ov.z = p0 * a.z + p1 * bq.z + p2 * cq.z + idv * vv.z;
  ov.w = p0 * a.w + p1 * bq.w + p2 * cq.w + idv * vv.w;
  float ss = ov.x * ov.x + ov.y * ov.y + ov.z * ov.z + ov.w * ov.w;
#pragma unroll
  for (int m = 1; m < 64; m <<= 1) ss += __shfl_xor(ss, m);
  float rms = rsqrtf(ss * (1.f / 256.f) + 1e-5f);
  float4 wn = *(const float4*)(onw + lane * 4);
  __hip_bfloat16 tmp[4] = {__float2bfloat16(ov.x * rms * wn.x),
                           __float2bfloat16(ov.y * rms * wn.y),
                           __float2bfloat16(ov.z * rms * wn.z),
                           __float2bfloat16(ov.w * rms * wn.w)};
  *(ushort4*)(o + base) = *(ushort4*)tmp;
}

extern "C" void kernel_launch(void* const* d_in, const int* in_sizes, int n_in,
                              void* d_out, int out_size, void* d_ws, size_t ws_size,
                              hipStream_t stream) {
  const float* x = (const float*)d_in[0];
  const float* Wq = (const float*)d_in[1];
  const float* Wk = (const float*)d_in[2];
  const float* Wv = (const float*)d_in[3];
  const float* Wb = (const float*)d_in[4];
  const float* conv_q = (const float*)d_in[5];
  const float* conv_k = (const float*)d_in[6];
  const float* conv_v = (const float*)d_in[7];
  const float* fir_s = (const float*)d_in[8];
  const float* fir_l = (const float*)d_in[9];
  const float* alpha_id = (const float*)d_in[10];
  const float* Wid = (const float*)d_in[11];
  const float* bidp = (const float*)d_in[12];
  const float* Wr1 = (const float*)d_in[13];
  const float* br1 = (const float*)d_in[14];
  const float* Wr2 = (const float*)d_in[15];
  const float* br2 = (const float*)d_in[16];
  const float* ltg = (const float*)d_in[17];
  const float* onw = (const float*)d_in[19];
  const float* Wo = (const float*)d_in[20];

  /* ---- workspace layout (f32 element offsets), peak ~197 MB (same as round 2) ----
     P   [0,        8388608)  pre (f32); later hmid (bf16 8192x2048)
     U   [8388608, 16777216)  xb (bf16 8192x1024) early; then u; phaseB in-place delta
     W   [16777216,25165824)  Wqt/Wkt/Wvt (bf16) early; then w; then rinb(bf16) +
                              Wr1t(bf16)@+4325376 + Wot(bf16)@+5406720; then omixb(bf16)@0
     ATT [25165824,26214400)  attn
     Q   [26214400,34603008)  q; later fs     K [34603008,42991616) k; later fl
     V   [42991616,51380224)  v
     BETA[51380224..) IDSC[51412992..) PMIX[51445760..51544064) */
  float* ws = (float*)d_ws;
  float* pre = ws + 0;
  float* ubuf = ws + 8388608;
  float* wbuf = ws + 16777216;
  float* attnbuf = ws + 25165824;
  float* qbuf = ws + 26214400;
  float* kbuf = ws + 34603008;
  float* vbuf = ws + 42991616;
  float* betabuf = ws + 51380224;
  float* idscbuf = ws + 51412992;
  float* pbuf = ws + 51445760;
  float* deltabuf = ubuf;
  __hip_bfloat16* xb = (__hip_bfloat16*)ubuf;
  __hip_bfloat16* Wqt = (__hip_bfloat16*)(wbuf);
  __hip_bfloat16* Wkt = (__hip_bfloat16*)(wbuf + 524288);
  __hip_bfloat16* Wvt = (__hip_bfloat16*)(wbuf + 1048576);
  __hip_bfloat16* rinb = (__hip_bfloat16*)(wbuf);
  __hip_bfloat16* Wr1t = (__hip_bfloat16*)(wbuf + 4325376);
  __hip_bfloat16* Wot = (__hip_bfloat16*)(wbuf + 5406720);
  __hip_bfloat16* omixb = (__hip_bfloat16*)(wbuf);
  __hip_bfloat16* hmid = (__hip_bfloat16*)pre;
  float* fsb = qbuf;
  float* flb = kbuf;

  dim3 blk(256);
  /* 0) prep: cast x, transpose+cast Wq/Wk/Wv */
  cast_bf16<<<dim3(ROWS), blk, 0, stream>>>(x, xb);
  transpose_cast<<<dim3(32, 32), blk, 0, stream>>>(Wq, Wqt, 1024, 1024, 1024);
  transpose_cast<<<dim3(32, 32), blk, 0, stream>>>(Wk, Wkt, 1024, 1024, 1024);
  transpose_cast<<<dim3(32, 32), blk, 0, stream>>>(Wv, Wvt, 1024, 1024, 1024);
  /* 1) projections (bf16 MFMA) + causal dwconv + silu */
  gemm_bf16<0, false><<<dim3(8, 64), blk, 0, stream>>>(xb, Wqt, nullptr, pre, ROWS, 1024, 1024);
  conv_silu<<<dim3(ROWS), blk, 0, stream>>>(pre, conv_q, qbuf);
  gemm_bf16<0, false><<<dim3(8, 64), blk, 0, stream>>>(xb, Wkt, nullptr, pre, ROWS, 1024, 1024);
  conv_silu<<<dim3(ROWS), blk, 0, stream>>>(pre, conv_k, kbuf);
  gemm_bf16<0, false><<<dim3(8, 64), blk, 0, stream>>>(xb, Wvt, nullptr, pre, ROWS, 1024, 1024);
  conv_silu<<<dim3(ROWS), blk, 0, stream>>>(pre, conv_v, vbuf);
  /* 2) beta / id_scale, l2norm */
  rowdot8<<<dim3(ROWS), blk, 0, stream>>>(x, Wb, Wid, alpha_id, bidp, betabuf, idscbuf);
  l2norm_qk<<<dim3(ROWS), blk, 0, stream>>>(qbuf, kbuf);
  /* 3) delta rule (phaseA overwrites xb/Wt scratch with u/w) */
  phaseA<<<dim3(BATCH * NH * NCHUNK), blk, 0, stream>>>(qbuf, kbuf, vbuf, betabuf, ubuf, wbuf, attnbuf);
  phaseB<<<dim3(BATCH * NH * 64), dim3(128), 0, stream>>>(qbuf, kbuf, ubuf, wbuf, attnbuf, deltabuf);
  /* 4) FIR into dead q,k */
  fir_kernel<<<dim3(ROWS), blk, 0, stream>>>(vbuf, fir_s, fir_l, fsb, flb);
  /* 5) router input (bf16, over dead w) + late weight prep */
  stats_router<<<dim3(ROWS), blk, 0, stream>>>(x, fsb, flb, deltabuf, rinb);
  transpose_cast<<<dim3(64, 33), blk, 0, stream>>>(Wr1, Wr1t, 1048, 2048, 1056);
  transpose_cast<<<dim3(32, 32), blk, 0, stream>>>(Wo, Wot, 1024, 1024, 1024);
  /* 6) router MLP layer 1 (MFMA, bias+gelu, bf16 out over dead pre) */
  gemm_bf16<1, true><<<dim3(16, 64), blk, 0, stream>>>(rinb, Wr1t, br1, hmid, ROWS, 2048, 1056);
  router_logits<<<dim3(ROWS), blk, 0, stream>>>(hmid, Wr2, br2, ltg, pbuf);
  /* 7) mixture + RMS norm (bf16 out over dead rinb) */
  omix<<<dim3(ROWS), blk, 0, stream>>>(fsb, flb, deltabuf, vbuf, pbuf, idscbuf, onw, omixb);
  /* 8) output projection (MFMA, f32 out) */
  gemm_bf16<0, false><<<dim3(8, 64), blk, 0, stream>>>(omixb, Wot, nullptr, d_out, ROWS, 1024, 1024);
}

// Round 4
// 2580.502 us; speedup vs baseline: 1.5491x; 1.0360x over previous
//
#include <hip/hip_runtime.h>
#include <hip/hip_bf16.h>
#include <math.h>

#define BATCH 2
#define SEQ 4096
#define DMODEL 1024
#define NH 4
#define DHEAD 256
#define NCHUNK 128
#define ROWS (BATCH * SEQ) /* 8192 */

typedef short s8v __attribute__((ext_vector_type(8)));   /* 8 bf16 in 4 VGPRs */
typedef float f4v __attribute__((ext_vector_type(4)));

__device__ __forceinline__ float sigm(float x) { return 1.0f / (1.0f + expf(-x)); }
__device__ __forceinline__ float siluf(float x) { return x / (1.0f + expf(-x)); }
__device__ __forceinline__ unsigned short f2b(float f) {
  __hip_bfloat16 h = __float2bfloat16(f);
  return *(unsigned short*)&h;
}

/* ---------- cast f32 -> bf16, n multiple of 1024, grid = n/1024 ---------- */
__global__ __launch_bounds__(256) void cast_bf16(
    const float* __restrict__ in, __hip_bfloat16* __restrict__ out) {
  long i = ((long)blockIdx.x * 256 + threadIdx.x) * 4;
  float4 v = *(const float4*)(in + i);
  __hip_bfloat16 tmp[4] = {__float2bfloat16(v.x), __float2bfloat16(v.y),
                           __float2bfloat16(v.z), __float2bfloat16(v.w)};
  *(ushort4*)(out + i) = *(ushort4*)tmp;
}

/* ---------- transpose K x N f32 -> N x Ks bf16 (zero-pad rows K..Ks) ----------
   grid (N/32, Ks/32), 256 threads */
__global__ __launch_bounds__(256) void transpose_cast(
    const float* __restrict__ W, __hip_bfloat16* __restrict__ Wt,
    int K, int N, int Ks) {
  __shared__ float tile[32][33];
  const int t = threadIdx.x;
  const int tx = t & 31, ty = t >> 5; /* ty 0..7 */
  const int kb = blockIdx.y * 32, nb = blockIdx.x * 32;
#pragma unroll
  for (int r = 0; r < 4; ++r) {
    int kk = kb + ty + 8 * r;
    tile[ty + 8 * r][tx] = (kk < K) ? W[(long)kk * N + nb + tx] : 0.f;
  }
  __syncthreads();
#pragma unroll
  for (int r = 0; r < 4; ++r) {
    Wt[(long)(nb + ty + 8 * r) * Ks + kb + tx] = __float2bfloat16(tile[tx][ty + 8 * r]);
  }
}

/* ---------------- bf16 MFMA GEMM: C = A(MxKs) * Bt(NxKs)^T ---------------- */
template <int ACT, bool BF16OUT>
__global__ __launch_bounds__(256) void gemm_bf16(
    const __hip_bfloat16* __restrict__ A, const __hip_bfloat16* __restrict__ Bt,
    const float* __restrict__ bias, void* __restrict__ Cv,
    int M, int N, int Ks) {
  __shared__ short As[128 * 32];
  __shared__ short Bs[128 * 32];
  const int t = threadIdx.x;
  const int wv = t >> 6;
  const int lane = t & 63;
  const int row0 = blockIdx.y * 128, col0 = blockIdx.x * 128;
  const int mq = (wv >> 1) * 64, nq = (wv & 1) * 64;
  const int ln15 = lane & 15;
  const int kq = (lane >> 4) * 8;
  const int sr = t >> 2;
  const int sc = (t & 3) * 8;
  const short* Ag = (const short*)A + (long)(row0 + sr) * Ks + sc;
  const short* Bg = (const short*)Bt + (long)(col0 + sr) * Ks + sc;
  const long rstep = (long)64 * Ks;

  f4v acc[4][4];
#pragma unroll
  for (int i = 0; i < 4; ++i)
#pragma unroll
    for (int j = 0; j < 4; ++j) acc[i][j] = (f4v){0.f, 0.f, 0.f, 0.f};

  uint4 a0 = *(const uint4*)(Ag);
  uint4 a1 = *(const uint4*)(Ag + rstep);
  uint4 b0 = *(const uint4*)(Bg);
  uint4 b1 = *(const uint4*)(Bg + rstep);
  for (int k0 = 0; k0 < Ks; k0 += 32) {
    __syncthreads();
    *(uint4*)&As[sr * 32 + sc] = a0;
    *(uint4*)&As[(sr + 64) * 32 + sc] = a1;
    *(uint4*)&Bs[sr * 32 + sc] = b0;
    *(uint4*)&Bs[(sr + 64) * 32 + sc] = b1;
    __syncthreads();
    if (k0 + 32 < Ks) {
      a0 = *(const uint4*)(Ag + k0 + 32);
      a1 = *(const uint4*)(Ag + rstep + k0 + 32);
      b0 = *(const uint4*)(Bg + k0 + 32);
      b1 = *(const uint4*)(Bg + rstep + k0 + 32);
    }
    s8v af[4], bf[4];
#pragma unroll
    for (int mt = 0; mt < 4; ++mt)
      af[mt] = *(const s8v*)&As[(mq + mt * 16 + ln15) * 32 + kq];
#pragma unroll
    for (int nt = 0; nt < 4; ++nt)
      bf[nt] = *(const s8v*)&Bs[(nq + nt * 16 + ln15) * 32 + kq];
#pragma unroll
    for (int mt = 0; mt < 4; ++mt)
#pragma unroll
      for (int nt = 0; nt < 4; ++nt)
        acc[mt][nt] = __builtin_amdgcn_mfma_f32_16x16x32_bf16(af[mt], bf[nt], acc[mt][nt], 0, 0, 0);
  }
  const int rbase = (lane >> 4) * 4;
#pragma unroll
  for (int mt = 0; mt < 4; ++mt) {
#pragma unroll
    for (int nt = 0; nt < 4; ++nt) {
      int gcol = col0 + nq + nt * 16 + ln15;
#pragma unroll
      for (int r = 0; r < 4; ++r) {
        int grow = row0 + mq + mt * 16 + rbase + r;
        float v = acc[mt][nt][r];
        if (ACT == 1) {
          v += bias[gcol];
          v = 0.5f * v * (1.0f + erff(v * 0.70710678118654752f));
        }
        if (BF16OUT) {
          ((__hip_bfloat16*)Cv)[(long)grow * N + gcol] = __float2bfloat16(v);
        } else {
          ((float*)Cv)[(long)grow * N + gcol] = v;
        }
      }
    }
  }
}

/* ---------- beta = sigmoid(x@Wb), idsc = 0.06 + sig(alpha)*sig(x@Wid + bid) ---------- */
__global__ __launch_bounds__(256) void rowdot8(
    const float* __restrict__ x, const float* __restrict__ Wb,
    const float* __restrict__ Wid, const float* __restrict__ alpha_id,
    const float* __restrict__ bidp, float* __restrict__ beta, float* __restrict__ idsc) {
  const int row = blockIdx.x;
  const int t = threadIdx.x;
  const float* xr = x + (long)row * DMODEL;
  float ab[4] = {0, 0, 0, 0}, ai[4] = {0, 0, 0, 0};
  for (int k = t; k < DMODEL; k += 256) {
    float xv = xr[k];
    float4 wb = *(const float4*)(Wb + k * 4);
    float4 wi = *(const float4*)(Wid + k * 4);
    ab[0] = fmaf(xv, wb.x, ab[0]); ab[1] = fmaf(xv, wb.y, ab[1]);
    ab[2] = fmaf(xv, wb.z, ab[2]); ab[3] = fmaf(xv, wb.w, ab[3]);
    ai[0] = fmaf(xv, wi.x, ai[0]); ai[1] = fmaf(xv, wi.y, ai[1]);
    ai[2] = fmaf(xv, wi.z, ai[2]); ai[3] = fmaf(xv, wi.w, ai[3]);
  }
#pragma unroll
  for (int m = 1; m < 64; m <<= 1) {
#pragma unroll
    for (int hh = 0; hh < 4; ++hh) {
      ab[hh] += __shfl_xor(ab[hh], m);
      ai[hh] += __shfl_xor(ai[hh], m);
    }
  }
  __shared__ float red[4][8];
  if ((t & 63) == 0) {
    int wv = t >> 6;
#pragma unroll
    for (int hh = 0; hh < 4; ++hh) {
      red[wv][hh] = ab[hh];
      red[wv][4 + hh] = ai[hh];
    }
  }
  __syncthreads();
  if (t < 8) {
    float s = red[0][t] + red[1][t] + red[2][t] + red[3][t];
    if (t < 4) {
      beta[(long)row * NH + t] = sigm(s);
    } else {
      int hh = t - 4;
      idsc[(long)row * NH + hh] = 0.06f + sigm(alpha_id[hh]) * sigm(s + bidp[hh]);
    }
  }
}

/* ---------- causal depthwise conv (K=4) + silu, single plane ---------- */
__global__ __launch_bounds__(256) void conv_silu(
    const float* __restrict__ pre, const float* __restrict__ cw, float* __restrict__ out) {
  const int row = blockIdx.x;
  const int l = row & (SEQ - 1);
  const int t = threadIdx.x;
  const int cb = t * 4;
  float wts[4][4];
#pragma unroll
  for (int cc = 0; cc < 4; ++cc) {
    float4 w4 = *(const float4*)(cw + (cb + cc) * 4);
    wts[cc][0] = w4.x; wts[cc][1] = w4.y; wts[cc][2] = w4.z; wts[cc][3] = w4.w;
  }
  float acc[4] = {0, 0, 0, 0};
#pragma unroll
  for (int tap = 0; tap < 4; ++tap) {
    int lr = l - 3 + tap;
    if (lr >= 0) {
      float4 xv = *(const float4*)(pre + (long)(row - 3 + tap) * DMODEL + cb);
      acc[0] = fmaf(wts[0][tap], xv.x, acc[0]);
      acc[1] = fmaf(wts[1][tap], xv.y, acc[1]);
      acc[2] = fmaf(wts[2][tap], xv.z, acc[2]);
      acc[3] = fmaf(wts[3][tap], xv.w, acc[3]);
    }
  }
  float4 ov = make_float4(siluf(acc[0]), siluf(acc[1]), siluf(acc[2]), siluf(acc[3]));
  *(float4*)(out + (long)row * DMODEL + cb) = ov;
}

/* ---------- in-place l2norm of q,k per (row, head) + bf16 copy of q ---------- */
__global__ __launch_bounds__(256) void l2norm_qk(
    float* __restrict__ q, float* __restrict__ k, __hip_bfloat16* __restrict__ qb16) {
  const int t = threadIdx.x;
  const int unit = blockIdx.x * 4 + (t >> 6);
  const int lane = t & 63;
  const int row = unit >> 2;
  const int h = unit & 3;
  const long base = (long)row * DMODEL + h * DHEAD + lane * 4;
  float4 q4 = *(const float4*)(q + base);
  float4 k4 = *(const float4*)(k + base);
  float sq = q4.x * q4.x + q4.y * q4.y + q4.z * q4.z + q4.w * q4.w;
  float sk = k4.x * k4.x + k4.y * k4.y + k4.z * k4.z + k4.w * k4.w;
#pragma unroll
  for (int m = 1; m < 64; m <<= 1) {
    sq += __shfl_xor(sq, m);
    sk += __shfl_xor(sk, m);
  }
  float rq = rsqrtf(sq + 1e-6f);
  float rk = rsqrtf(sk + 1e-6f);
  q4.x *= rq; q4.y *= rq; q4.z *= rq; q4.w *= rq;
  k4.x *= rk; k4.y *= rk; k4.z *= rk; k4.w *= rk;
  *(float4*)(q + base) = q4;
  *(float4*)(k + base) = k4;
  ushort4 qb;
  qb.x = f2b(q4.x); qb.y = f2b(q4.y); qb.z = f2b(q4.z); qb.w = f2b(q4.w);
  *(ushort4*)(qb16 + base) = qb;
}

/* ---------- phase A: per-chunk T solve; emits u (f32), w (bf16), kT (bf16),
   attn (bf16). block per (b,h,chunk) ---------- */
__global__ __launch_bounds__(256) void phaseA(
    const float* __restrict__ qn, const float* __restrict__ kn, const float* __restrict__ v,
    const float* __restrict__ beta, float* __restrict__ u,
    __hip_bfloat16* __restrict__ wb16, __hip_bfloat16* __restrict__ kTb16,
    __hip_bfloat16* __restrict__ attnb16) {
  __shared__ float Ks[32][256];
  __shared__ float T[32][33];
  __shared__ float bet[32];
  const int bid = blockIdx.x;
  const int c = bid & (NCHUNK - 1);
  const int h = (bid >> 7) & 3;
  const int b = bid >> 9;
  const int bh = b * NH + h;
  const int l0 = c * 32;
  const int t = threadIdx.x;
  const int wv = t >> 6;
  const int lane = t & 63;

#pragma unroll
  for (int r = 0; r < 8; ++r) {
    int idx = t + 256 * r;
    int i = idx >> 6;
    int f = (idx & 63) * 4;
    long gq = ((long)(b * SEQ + l0 + i)) * DMODEL + h * DHEAD + f;
    *(float4*)&Ks[i][f] = *(const float4*)(kn + gq);
  }
  if (t < 32) bet[t] = beta[(long)(b * SEQ + l0 + t) * NH + h];
  __syncthreads();

  /* T = strict-lower(-(kb kn^T)) */
  {
#pragma unroll
    for (int ii = 0; ii < 8; ++ii) {
      const int i = wv * 8 + ii;
      float4 a = *(const float4*)&Ks[i][lane * 4];
      float nbi = -bet[i];
      for (int j = 0; j < 32; ++j) {
        float val = 0.f;
        if (j < i) {
          float4 bb = *(const float4*)&Ks[j][lane * 4];
          float pd = a.x * bb.x + a.y * bb.y + a.z * bb.z + a.w * bb.w;
#pragma unroll
          for (int m = 1; m < 64; m <<= 1) pd += __shfl_xor(pd, m);
          val = nbi * pd;
        }
        if (lane == 0) T[i][j] = val;
      }
    }
  }
  __syncthreads();

  /* forward substitution + add I + fold beta into columns */
  if (t < 32) {
    const int l = t;
    for (int i = 1; i < 32; ++i) {
      float s = 0.f;
      for (int j = 0; j < i; ++j) s = fmaf(T[i][j], T[j][l], s);
      T[i][l] += s;
    }
    for (int i = 0; i < 32; ++i) {
      float val = T[i][l] + (i == l ? 1.f : 0.f);
      T[i][l] = val * bet[l];
    }
  }
  __syncthreads();

  /* u = T' @ v (f32 out), w = T' @ kn (bf16 out) ; thread = column d */
  {
    const int d = t;
    float acc[32];
#pragma unroll
    for (int i = 0; i < 32; ++i) acc[i] = 0.f;
    for (int j = 0; j < 32; ++j) {
      float vv = v[((long)(b * SEQ + l0 + j)) * DMODEL + h * DHEAD + d];
#pragma unroll
      for (int i = 0; i < 32; ++i) acc[i] = fmaf(T[i][j], vv, acc[i]);
    }
    long ubase = ((long)bh * SEQ + l0) * DHEAD + d;
#pragma unroll
    for (int i = 0; i < 32; ++i) u[ubase + (long)i * DHEAD] = acc[i];
#pragma unroll
    for (int i = 0; i < 32; ++i) acc[i] = 0.f;
    for (int j = 0; j < 32; ++j) {
      float kv = Ks[j][d];
#pragma unroll
      for (int i = 0; i < 32; ++i) acc[i] = fmaf(T[i][j], kv, acc[i]);
    }
#pragma unroll
    for (int i = 0; i < 32; ++i) wb16[ubase + (long)i * DHEAD] = __float2bfloat16(acc[i]);
  }

  /* kT emit: kTb16[bh][c][s*32+i] = Ks[i][s], bf16; thread = s */
  {
    const int s = t;
    unsigned short* kb = (unsigned short*)kTb16 + ((long)bh * NCHUNK + c) * 8192 + (long)s * 32;
#pragma unroll
    for (int i4 = 0; i4 < 8; ++i4) {
      ushort4 pk;
      pk.x = f2b(Ks[i4 * 4 + 0][s]);
      pk.y = f2b(Ks[i4 * 4 + 1][s]);
      pk.z = f2b(Ks[i4 * 4 + 2][s]);
      pk.w = f2b(Ks[i4 * 4 + 3][s]);
      *(ushort4*)(kb + i4 * 4) = pk;
    }
  }

  /* attn = tril(qn kn^T) incl diag -> bf16 */
  {
    long abase = ((long)bh * NCHUNK + c) * 1024;
#pragma unroll
    for (int ii = 0; ii < 8; ++ii) {
      const int i = wv * 8 + ii;
      const float* qrow = qn + ((long)(b * SEQ + l0 + i)) * DMODEL + h * DHEAD;
      float4 a = *(const float4*)(qrow + lane * 4);
      for (int j = 0; j < 32; ++j) {
        float val = 0.f;
        if (j <= i) {
          float4 bb = *(const float4*)&Ks[j][lane * 4];
          float pd = a.x * bb.x + a.y * bb.y + a.z * bb.z + a.w * bb.w;
#pragma unroll
          for (int m = 1; m < 64; m <<= 1) pd += __shfl_xor(pd, m);
          val = pd;
        }
        if (lane == 0) attnb16[abase + i * 32 + j] = __float2bfloat16(val);
      }
    }
  }
}

/* ---------- phase B v3 (MFMA): 32 blocks = 8 (b,h) x 4 DV-groups of 64.
   S slice (256 x 64) persists in 64 f32 MFMA accumulators/lane.
   Per chunk: S->bf16 LDS (C/D -> B-operand transform), then
   w@S, q@S, attn@u2, S += kT@u2 as 16x16x32 bf16 MFMAs.
   A-operands (w,q,kT,attn) read as coalesced 16B global fragments (bf16,
   pre-materialized by phaseA / l2norm). u stays f32; delta aliases u in place
   (each u element read by the same lane that later overwrites it, same chunk).
   2 barriers/chunk: X after S->Stb conversion, Y after U2T write; hazard
   analysis: Stb reads end before Y, U2T reads end before next X. ---------- */
__global__ __launch_bounds__(256) void phaseB(
    const __hip_bfloat16* __restrict__ qb,   /* [b*S][1024] bf16 l2-normed q */
    const __hip_bfloat16* __restrict__ wb,   /* [bh][l][256] bf16 */
    const __hip_bfloat16* __restrict__ kTb,  /* [bh][c][s*32+i] bf16 */
    const __hip_bfloat16* __restrict__ attnb,/* [bh][c][i*32+j] bf16 */
    const float* u, float* delta /* == u */) {
  __shared__ short Stb[64 * 264]; /* [dv][s], pad 8: ~2-way banks (free) */
  __shared__ short U2T[64 * 40];  /* [dv][i], pad 8 */
  const int bid = blockIdx.x;
  const int g = bid & 3;
  const int bh = bid >> 2;
  const int b = bh >> 2, h = bh & 3;
  const int d0 = g * 64;
  const int t = threadIdx.x;
  const int wv = t >> 6, lane = t & 63;
  const int ln15 = lane & 15, qw = lane >> 4;
  const int kq = qw * 8, rbase = qw * 4;

  f4v Sacc[4][4]; /* [mi][nt]: s-tile 4*wv+mi, dv-tile nt */
#pragma unroll
  for (int mi = 0; mi < 4; ++mi)
#pragma unroll
    for (int nt = 0; nt < 4; ++nt) Sacc[mi][nt] = (f4v){0.f, 0.f, 0.f, 0.f};

  const short* wbase = (const short*)wb + (long)bh * SEQ * 256;
  const short* qbase = (const short*)qb + (long)b * SEQ * 1024 + h * 256;
  const short* kTbase = (const short*)kTb + (long)bh * NCHUNK * 8192;
  const short* atbase = (const short*)attnb + (long)bh * NCHUNK * 1024;
  const int dv = wv * 16 + ln15; /* this wave's output dv lane */

  for (int c = 0; c < NCHUNK; ++c) {
    const int l0 = c * 32;
    /* (1) S_{c-1} -> Stb bf16 [dv][s]; wave wv covers s in [64wv,64wv+64) */
#pragma unroll
    for (int mi = 0; mi < 4; ++mi) {
      const int s0 = wv * 64 + mi * 16 + rbase;
#pragma unroll
      for (int nt = 0; nt < 4; ++nt) {
        ushort4 pk;
        pk.x = f2b(Sacc[mi][nt][0]);
        pk.y = f2b(Sacc[mi][nt][1]);
        pk.z = f2b(Sacc[mi][nt][2]);
        pk.w = f2b(Sacc[mi][nt][3]);
        *(ushort4*)&Stb[(nt * 16 + ln15) * 264 + s0] = pk;
      }
    }
    __syncthreads(); /* X */
    /* (2) B-frags of S for this wave's dv-slice (nt = wv), all 8 k-steps */
    s8v bfr[8];
#pragma unroll
    for (int ks = 0; ks < 8; ++ks)
      bfr[ks] = *(const s8v*)&Stb[(wv * 16 + ln15) * 264 + ks * 32 + kq];
    /* w@S -> dw (C/D layout: row i = mt*16+rbase+r, col = dv) */
    const short* wr0 = wbase + (long)(l0 + ln15) * 256 + kq;
    const short* wr1 = wbase + (long)(l0 + 16 + ln15) * 256 + kq;
    f4v dw0 = (f4v){0.f, 0.f, 0.f, 0.f}, dw1 = (f4v){0.f, 0.f, 0.f, 0.f};
#pragma unroll
    for (int ks = 0; ks < 8; ++ks) {
      s8v a0 = *(const s8v*)(wr0 + ks * 32);
      s8v a1 = *(const s8v*)(wr1 + ks * 32);
      dw0 = __builtin_amdgcn_mfma_f32_16x16x32_bf16(a0, bfr[ks], dw0, 0, 0, 0);
      dw1 = __builtin_amdgcn_mfma_f32_16x16x32_bf16(a1, bfr[ks], dw1, 0, 0, 0);
    }
    /* q@S -> o */
    const short* qr0 = qbase + (long)(l0 + ln15) * 1024 + kq;
    const short* qr1 = qbase + (long)(l0 + 16 + ln15) * 1024 + kq;
    f4v o0 = (f4v){0.f, 0.f, 0.f, 0.f}, o1 = (f4v){0.f, 0.f, 0.f, 0.f};
#pragma unroll
    for (int ks = 0; ks < 8; ++ks) {
      s8v a0 = *(const s8v*)(qr0 + ks * 1024); /* q row stride = 1024 bf16 */
      s8v a1 = *(const s8v*)(qr1 + ks * 1024);
      /* NOTE: k advances by 32 along the row: offset ks*32 within the head */
      a0 = *(const s8v*)(qr0 + ks * 32);
      a1 = *(const s8v*)(qr1 + ks * 32);
      o0 = __builtin_amdgcn_mfma_f32_16x16x32_bf16(a0, bfr[ks], o0, 0, 0, 0);
      o1 = __builtin_amdgcn_mfma_f32_16x16x32_bf16(a1, bfr[ks], o1, 0, 0, 0);
    }
    /* u2 = u - w@S (f32), stash transposed bf16 for B-operands */
    float u2a[4], u2b[4];
#pragma unroll
    for (int r = 0; r < 4; ++r) {
      u2a[r] = u[((long)bh * SEQ + l0 + rbase + r) * 256 + d0 + dv] - dw0[r];
      u2b[r] = u[((long)bh * SEQ + l0 + 16 + rbase + r) * 256 + d0 + dv] - dw1[r];
    }
    {
      ushort4 pa, pb;
      pa.x = f2b(u2a[0]); pa.y = f2b(u2a[1]); pa.z = f2b(u2a[2]); pa.w = f2b(u2a[3]);
      pb.x = f2b(u2b[0]); pb.y = f2b(u2b[1]); pb.z = f2b(u2b[2]); pb.w = f2b(u2b[3]);
      *(ushort4*)&U2T[dv * 40 + rbase] = pa;
      *(ushort4*)&U2T[dv * 40 + 16 + rbase] = pb;
    }
    __syncthreads(); /* Y */
    /* (3) attn@u2 -> o ; delta write ; S += kT@u2 */
    s8v bu[4];
#pragma unroll
    for (int nt = 0; nt < 4; ++nt)
      bu[nt] = *(const s8v*)&U2T[(nt * 16 + ln15) * 40 + kq];
    {
      s8v at0 = *(const s8v*)(atbase + (long)c * 1024 + ln15 * 32 + kq);
      s8v at1 = *(const s8v*)(atbase + (long)c * 1024 + (16 + ln15) * 32 + kq);
      o0 = __builtin_amdgcn_mfma_f32_16x16x32_bf16(at0, bu[wv], o0, 0, 0, 0);
      o1 = __builtin_amdgcn_mfma_f32_16x16x32_bf16(at1, bu[wv], o1, 0, 0, 0);
    }
#pragma unroll
    for (int r = 0; r < 4; ++r) {
      delta[((long)bh * SEQ + l0 + rbase + r) * 256 + d0 + dv] = o0[r];
      delta[((long)bh * SEQ + l0 + 16 + rbase + r) * 256 + d0 + dv] = o1[r];
    }
    {
      s8v af[4];
#pragma unroll
      for (int mi = 0; mi < 4; ++mi)
        af[mi] = *(const s8v*)(kTbase + (long)c * 8192 + ((wv * 4 + mi) * 16 + ln15) * 32 + kq);
#pragma unroll
      for (int mi = 0; mi < 4; ++mi)
#pragma unroll
        for (int nt = 0; nt < 4; ++nt)
          Sacc[mi][nt] = __builtin_amdgcn_mfma_f32_16x16x32_bf16(af[mi], bu[nt], Sacc[mi][nt], 0, 0, 0);
    }
    /* no tail barrier: next X orders U2T/Stb reuse (see header comment) */
  }
}

/* ---------- FIR short(3)+long(31) causal depthwise convs on vh ---------- */
__global__ __launch_bounds__(256) void fir_kernel(
    const float* __restrict__ v, const float* __restrict__ fshort,
    const float* __restrict__ flong, float* __restrict__ fs, float* __restrict__ fl) {
  const int row = blockIdx.x;
  const int l = row & (SEQ - 1);
  const int t = threadIdx.x;
  const int cb = t * 4;
  float4 accl = make_float4(0, 0, 0, 0);
  float4 accs = make_float4(0, 0, 0, 0);
  for (int j = 0; j < 31; ++j) {
    int lr = l - 30 + j;
    if (lr < 0) continue;
    float4 xv = *(const float4*)(v + (long)(row - 30 + j) * DMODEL + cb);
    float w0 = flong[(cb + 0) * 31 + j];
    float w1 = flong[(cb + 1) * 31 + j];
    float w2 = flong[(cb + 2) * 31 + j];
    float w3 = flong[(cb + 3) * 31 + j];
    accl.x = fmaf(w0, xv.x, accl.x);
    accl.y = fmaf(w1, xv.y, accl.y);
    accl.z = fmaf(w2, xv.z, accl.z);
    accl.w = fmaf(w3, xv.w, accl.w);
    if (j >= 28) {
      int tp = j - 28;
      float s0 = fshort[(cb + 0) * 3 + tp];
      float s1 = fshort[(cb + 1) * 3 + tp];
      float s2 = fshort[(cb + 2) * 3 + tp];
      float s3 = fshort[(cb + 3) * 3 + tp];
      accs.x = fmaf(s0, xv.x, accs.x);
      accs.y = fmaf(s1, xv.y, accs.y);
      accs.z = fmaf(s2, xv.z, accs.z);
      accs.w = fmaf(s3, xv.w, accs.w);
    }
  }
  *(float4*)(fs + (long)row * DMODEL + cb) = accs;
  *(float4*)(fl + (long)row * DMODEL + cb) = accl;
}

/* ---------- stats + assemble router input as bf16 (stride 1056, zero pad) ---------- */
__global__ __launch_bounds__(256) void stats_router(
    const float* __restrict__ x, const float* __restrict__ fs,
    const float* __restrict__ fl, const float* __restrict__ dl,
    __hip_bfloat16* __restrict__ rinb) {
  const int row = blockIdx.x;
  const int b = row >> 12;
  const int l = row & (SEQ - 1);
  const int t = threadIdx.x;
  float4 xv = *(const float4*)(x + (long)row * DMODEL + t * 4);
  {
    __hip_bfloat16 tmp[4] = {__float2bfloat16(xv.x), __float2bfloat16(xv.y),
                             __float2bfloat16(xv.z), __float2bfloat16(xv.w)};
    *(ushort4*)(rinb + (long)row * 1056 + t * 4) = *(ushort4*)tmp;
  }
  if (t < 8) rinb[(long)row * 1056 + 1048 + t] = __float2bfloat16(0.f);
  const int h = t >> 6;
  const int lane = t & 63;
  const long base = (long)row * DMODEL + h * DHEAD + lane * 4;
  const long dbase = ((long)(b * NH + h) * SEQ + l) * DHEAD + lane * 4;
  float4 a = *(const float4*)(fs + base);
  float4 bq = *(const float4*)(fl + base);
  float4 cq = *(const float4*)(dl + dbase);
  float s[6];
  s[0] = a.x + a.y + a.z + a.w;
  s[1] = a.x * a.x + a.y * a.y + a.z * a.z + a.w * a.w;
  s[2] = bq.x + bq.y + bq.z + bq.w;
  s[3] = bq.x * bq.x + bq.y * bq.y + bq.z * bq.z + bq.w * bq.w;
  s[4] = cq.x + cq.y + cq.z + cq.w;
  s[5] = cq.x * cq.x + cq.y * cq.y + cq.z * cq.z + cq.w * cq.w;
#pragma unroll
  for (int m = 1; m < 64; m <<= 1)
#pragma unroll
    for (int j = 0; j < 6; ++j) s[j] += __shfl_xor(s[j], m);
  if (lane == 0) {
    __hip_bfloat16* rb = rinb + (long)row * 1056 + 1024;
    float m0 = s[0] * (1.f / 256.f);
    float m1 = s[2] * (1.f / 256.f);
    float m2 = s[4] * (1.f / 256.f);
    rb[h] = __float2bfloat16(m0);
    rb[4 + h] = __float2bfloat16(sqrtf(fmaxf(s[1] * (1.f / 256.f) - m0 * m0, 0.f)));
    rb[8 + h] = __float2bfloat16(m1);
    rb[12 + h] = __float2bfloat16(sqrtf(fmaxf(s[3] * (1.f / 256.f) - m1 * m1, 0.f)));
    rb[16 + h] = __float2bfloat16(m2);
    rb[20 + h] = __float2bfloat16(sqrtf(fmaxf(s[5] * (1.f / 256.f) - m2 * m2, 0.f)));
  }
}

/* ---------- logits from bf16 hmid ; p = softmax(logits/tau)*0.925+0.025 ---------- */
__global__ __launch_bounds__(256) void router_logits(
    const __hip_bfloat16* __restrict__ hmid, const float* __restrict__ Wr2,
    const float* __restrict__ br2, const float* __restrict__ ltg, float* __restrict__ p) {
  const int row = blockIdx.x;
  const int t = threadIdx.x;
  float acc[12];
#pragma unroll
  for (int j = 0; j < 12; ++j) acc[j] = 0.f;
  const __hip_bfloat16* hr = hmid + (long)row * 2048;
  for (int k = t; k < 2048; k += 256) {
    float hv = __bfloat162float(hr[k]);
    const float* wr = Wr2 + k * 12;
#pragma unroll
    for (int j = 0; j < 12; ++j) acc[j] = fmaf(hv, wr[j], acc[j]);
  }
#pragma unroll
  for (int m = 1; m < 64; m <<= 1)
#pragma unroll
    for (int j = 0; j < 12; ++j) acc[j] += __shfl_xor(acc[j], m);
  __shared__ float red[4][12];
  if ((t & 63) == 0) {
    int wv = t >> 6;
#pragma unroll
    for (int j = 0; j < 12; ++j) red[wv][j] = acc[j];
  }
  __syncthreads();
  if (t < 4) {
    const int h = t;
    float l3[3];
#pragma unroll
    for (int j = 0; j < 3; ++j) {
      int col = h * 3 + j;
      l3[j] = red[0][col] + red[1][col] + red[2][col] + red[3][col] + br2[col];
    }
    float inv_tau = expf(-ltg[h >> 1]);
    float y0 = l3[0] * inv_tau, y1 = l3[1] * inv_tau, y2 = l3[2] * inv_tau;
    float mx = fmaxf(y0, fmaxf(y1, y2));
    float e0 = expf(y0 - mx), e1 = expf(y1 - mx), e2 = expf(y2 - mx);
    float inv = 1.f / (e0 + e1 + e2);
    p[(long)row * 12 + h * 3 + 0] = e0 * inv * 0.925f + 0.025f;
    p[(long)row * 12 + h * 3 + 1] = e1 * inv * 0.925f + 0.025f;
    p[(long)row * 12 + h * 3 + 2] = e2 * inv * 0.925f + 0.025f;
  }
}

/* ---------- mixture + identity + RMS norm -> bf16 out. delta layout (B,H,L,DV). ---------- */
__global__ __launch_bounds__(256) void omix(
    const float* __restrict__ fs, const float* __restrict__ fl,
    const float* __restrict__ dl, const float* __restrict__ vh,
    const float* __restrict__ p, const float* __restrict__ idsc,
    const float* __restrict__ onw, __hip_bfloat16* __restrict__ o) {
  const int row = blockIdx.x;
  const int b = row >> 12;
  const int l = row & (SEQ - 1);
  const int t = threadIdx.x;
  const int h = t >> 6;
  const int lane = t & 63;
  const long base = (long)row * DMODEL + h * DHEAD + lane * 4;
  const long dbase = ((long)(b * NH + h) * SEQ + l) * DHEAD + lane * 4;
  float p0 = p[(long)row * 12 + h * 3 + 0];
  float p1 = p[(long)row * 12 + h * 3 + 1];
  float p2 = p[(long)row * 12 + h * 3 + 2];
  float idv = idsc[(long)row * NH + h];
  float4 a = *(const float4*)(fs + base);
  float4 bq = *(const float4*)(fl + base);
  float4 cq = *(const float4*)(dl + dbase);
  float4 vv = *(const float4*)(vh + base);
  float4 ov;
  ov.x = p0 * a.x + p1 * bq.x + p2 * cq.x + idv * vv.x;
  ov.y = p0 * a.y + p1 * bq.y + p2 * cq.y + idv * vv.y;
  ov.z = p0 * a.z + p1 * bq.z + p2 * cq.z + idv * vv.z;
  ov.w = p0 * a.w + p1 * bq.w + p2 * cq.w + idv * vv.w;
  float ss = ov.x * ov.x + ov.y * ov.y + ov.z * ov.z + ov.w * ov.w;
#pragma unroll
  for (int m = 1; m < 64; m <<= 1) ss += __shfl_xor(ss, m);
  float rms = rsqrtf(ss * (1.f / 256.f) + 1e-5f);
  float4 wn = *(const float4*)(onw + lane * 4);
  __hip_bfloat16 tmp[4] = {__float2bfloat16(ov.x * rms * wn.x),
                           __float2bfloat16(ov.y * rms * wn.y),
                           __float2bfloat16(ov.z * rms * wn.z),
                           __float2bfloat16(ov.w * rms * wn.w)};
  *(ushort4*)(o + base) = *(ushort4*)tmp;
}

extern "C" void kernel_launch(void* const* d_in, const int* in_sizes, int n_in,
                              void* d_out, int out_size, void* d_ws, size_t ws_size,
                              hipStream_t stream) {
  const float* x = (const float*)d_in[0];
  const float* Wq = (const float*)d_in[1];
  const float* Wk = (const float*)d_in[2];
  const float* Wv = (const float*)d_in[3];
  const float* Wb = (const float*)d_in[4];
  const float* conv_q = (const float*)d_in[5];
  const float* conv_k = (const float*)d_in[6];
  const float* conv_v = (const float*)d_in[7];
  const float* fir_s = (const float*)d_in[8];
  const float* fir_l = (const float*)d_in[9];
  const float* alpha_id = (const float*)d_in[10];
  const float* Wid = (const float*)d_in[11];
  const float* bidp = (const float*)d_in[12];
  const float* Wr1 = (const float*)d_in[13];
  const float* br1 = (const float*)d_in[14];
  const float* Wr2 = (const float*)d_in[15];
  const float* br2 = (const float*)d_in[16];
  const float* ltg = (const float*)d_in[17];
  const float* onw = (const float*)d_in[19];
  const float* Wo = (const float*)d_in[20];

  /* ---- workspace layout (f32 element offsets), peak ~206 MB (same as r3) ----
     P   [0,        8388608)  pre (f32); qb16 (bf16, first half) after conv v;
                              later hmid (bf16 8192x2048, full region)
     U   [8388608, 16777216)  xb (bf16) early; then u (f32); phaseB in-place delta
     W   [16777216,25165824)  Wqt/Wkt/Wvt (bf16) early; then wb16 (bf16, first
                              half) + kTb16 (bf16, second half); then rinb(bf16)
                              + Wr1t + Wot; then omixb(bf16)
     ATT [25165824,26214400)  attnb16 (bf16, 2MB of 4MB region)
     Q   [26214400,34603008)  q f32; later fs    K [34603008,42991616) k; later fl
     V   [42991616,51380224)  v
     BETA[51380224..) IDSC[51412992..) PMIX[51445760..51544064) */
  float* ws = (float*)d_ws;
  float* pre = ws + 0;
  float* ubuf = ws + 8388608;
  float* wbuf = ws + 16777216;
  float* attnbuf = ws + 25165824;
  float* qbuf = ws + 26214400;
  float* kbuf = ws + 34603008;
  float* vbuf = ws + 42991616;
  float* betabuf = ws + 51380224;
  float* idscbuf = ws + 51412992;
  float* pbuf = ws + 51445760;
  float* deltabuf = ubuf;
  __hip_bfloat16* xb = (__hip_bfloat16*)ubuf;
  __hip_bfloat16* Wqt = (__hip_bfloat16*)(wbuf);
  __hip_bfloat16* Wkt = (__hip_bfloat16*)(wbuf + 524288);
  __hip_bfloat16* Wvt = (__hip_bfloat16*)(wbuf + 1048576);
  __hip_bfloat16* wb16 = (__hip_bfloat16*)wbuf;                 /* 8.4M bf16 */
  __hip_bfloat16* kTb16 = (__hip_bfloat16*)wbuf + 8388608;      /* 8.4M bf16 */
  __hip_bfloat16* attnb16 = (__hip_bfloat16*)attnbuf;           /* 1M bf16 */
  __hip_bfloat16* qb16 = (__hip_bfloat16*)pre;                  /* 8.4M bf16 */
  __hip_bfloat16* rinb = (__hip_bfloat16*)(wbuf);
  __hip_bfloat16* Wr1t = (__hip_bfloat16*)(wbuf + 4325376);
  __hip_bfloat16* Wot = (__hip_bfloat16*)(wbuf + 5406720);
  __hip_bfloat16* omixb = (__hip_bfloat16*)(wbuf);
  __hip_bfloat16* hmid = (__hip_bfloat16*)pre;
  float* fsb = qbuf;
  float* flb = kbuf;

  dim3 blk(256);
  /* 0) prep: cast x, transpose+cast Wq/Wk/Wv */
  cast_bf16<<<dim3(ROWS), blk, 0, stream>>>(x, xb);
  transpose_cast<<<dim3(32, 32), blk, 0, stream>>>(Wq, Wqt, 1024, 1024, 1024);
  transpose_cast<<<dim3(32, 32), blk, 0, stream>>>(Wk, Wkt, 1024, 1024, 1024);
  transpose_cast<<<dim3(32, 32), blk, 0, stream>>>(Wv, Wvt, 1024, 1024, 1024);
  /* 1) projections (bf16 MFMA) + causal dwconv + silu */
  gemm_bf16<0, false><<<dim3(8, 64), blk, 0, stream>>>(xb, Wqt, nullptr, pre, ROWS, 1024, 1024);
  conv_silu<<<dim3(ROWS), blk, 0, stream>>>(pre, conv_q, qbuf);
  gemm_bf16<0, false><<<dim3(8, 64), blk, 0, stream>>>(xb, Wkt, nullptr, pre, ROWS, 1024, 1024);
  conv_silu<<<dim3(ROWS), blk, 0, stream>>>(pre, conv_k, kbuf);
  gemm_bf16<0, false><<<dim3(8, 64), blk, 0, stream>>>(xb, Wvt, nullptr, pre, ROWS, 1024, 1024);
  conv_silu<<<dim3(ROWS), blk, 0, stream>>>(pre, conv_v, vbuf);
  /* 2) beta / id_scale, l2norm (+ bf16 q copy over dead pre) */
  rowdot8<<<dim3(ROWS), blk, 0, stream>>>(x, Wb, Wid, alpha_id, bidp, betabuf, idscbuf);
  l2norm_qk<<<dim3(ROWS), blk, 0, stream>>>(qbuf, kbuf, qb16);
  /* 3) delta rule: phaseA emits u(f32) + w/kT/attn(bf16); phaseB = MFMA scan */
  phaseA<<<dim3(BATCH * NH * NCHUNK), blk, 0, stream>>>(qbuf, kbuf, vbuf, betabuf, ubuf, wb16, kTb16, attnb16);
  phaseB<<<dim3(BATCH * NH * 4), blk, 0, stream>>>(qb16, wb16, kTb16, attnb16, ubuf, deltabuf);
  /* 4) FIR into dead q,k */
  fir_kernel<<<dim3(ROWS), blk, 0, stream>>>(vbuf, fir_s, fir_l, fsb, flb);
  /* 5) router input (bf16, over dead w region) + late weight prep */
  stats_router<<<dim3(ROWS), blk, 0, stream>>>(x, fsb, flb, deltabuf, rinb);
  transpose_cast<<<dim3(64, 33), blk, 0, stream>>>(Wr1, Wr1t, 1048, 2048, 1056);
  transpose_cast<<<dim3(32, 32), blk, 0, stream>>>(Wo, Wot, 1024, 1024, 1024);
  /* 6) router MLP layer 1 (MFMA, bias+gelu, bf16 out over dead pre) */
  gemm_bf16<1, true><<<dim3(16, 64), blk, 0, stream>>>(rinb, Wr1t, br1, hmid, ROWS, 2048, 1056);
  router_logits<<<dim3(ROWS), blk, 0, stream>>>(hmid, Wr2, br2, ltg, pbuf);
  /* 7) mixture + RMS norm (bf16 out over dead rinb) */
  omix<<<dim3(ROWS), blk, 0, stream>>>(fsb, flb, deltabuf, vbuf, pbuf, idscbuf, onw, omixb);
  /* 8) output projection (MFMA, f32 out) */
  gemm_bf16<0, false><<<dim3(8, 64), blk, 0, stream>>>(omixb, Wot, nullptr, d_out, ROWS, 1024, 1024);
}

// Round 5
// 2485.717 us; speedup vs baseline: 1.6082x; 1.0381x over previous
//
#include <hip/hip_runtime.h>
#include <hip/hip_bf16.h>
#include <math.h>

#define BATCH 2
#define SEQ 4096
#define DMODEL 1024
#define NH 4
#define DHEAD 256
#define NCHUNK 128
#define ROWS (BATCH * SEQ) /* 8192 */

typedef short s8v __attribute__((ext_vector_type(8)));   /* 8 bf16 in 4 VGPRs */
typedef float f4v __attribute__((ext_vector_type(4)));

__device__ __forceinline__ float sigm(float x) { return 1.0f / (1.0f + expf(-x)); }
__device__ __forceinline__ float siluf(float x) { return x / (1.0f + expf(-x)); }
__device__ __forceinline__ unsigned short f2b(float f) {
  __hip_bfloat16 h = __float2bfloat16(f);
  return *(unsigned short*)&h;
}

/* ---------- cast f32 -> bf16, n multiple of 1024, grid = n/1024 ---------- */
__global__ __launch_bounds__(256) void cast_bf16(
    const float* __restrict__ in, __hip_bfloat16* __restrict__ out) {
  long i = ((long)blockIdx.x * 256 + threadIdx.x) * 4;
  float4 v = *(const float4*)(in + i);
  __hip_bfloat16 tmp[4] = {__float2bfloat16(v.x), __float2bfloat16(v.y),
                           __float2bfloat16(v.z), __float2bfloat16(v.w)};
  *(ushort4*)(out + i) = *(ushort4*)tmp;
}

/* ---------- transpose K x N f32 -> N x Ks bf16 (zero-pad rows K..Ks) ---------- */
__global__ __launch_bounds__(256) void transpose_cast(
    const float* __restrict__ W, __hip_bfloat16* __restrict__ Wt,
    int K, int N, int Ks) {
  __shared__ float tile[32][33];
  const int t = threadIdx.x;
  const int tx = t & 31, ty = t >> 5;
  const int kb = blockIdx.y * 32, nb = blockIdx.x * 32;
#pragma unroll
  for (int r = 0; r < 4; ++r) {
    int kk = kb + ty + 8 * r;
    tile[ty + 8 * r][tx] = (kk < K) ? W[(long)kk * N + nb + tx] : 0.f;
  }
  __syncthreads();
#pragma unroll
  for (int r = 0; r < 4; ++r) {
    Wt[(long)(nb + ty + 8 * r) * Ks + kb + tx] = __float2bfloat16(tile[tx][ty + 8 * r]);
  }
}

/* ---------------- bf16 MFMA GEMM: C = A(MxKs) * Bt(NxKs)^T ---------------- */
template <int ACT, bool BF16OUT>
__global__ __launch_bounds__(256) void gemm_bf16(
    const __hip_bfloat16* __restrict__ A, const __hip_bfloat16* __restrict__ Bt,
    const float* __restrict__ bias, void* __restrict__ Cv,
    int M, int N, int Ks) {
  __shared__ short As[128 * 32];
  __shared__ short Bs[128 * 32];
  const int t = threadIdx.x;
  const int wv = t >> 6;
  const int lane = t & 63;
  const int row0 = blockIdx.y * 128, col0 = blockIdx.x * 128;
  const int mq = (wv >> 1) * 64, nq = (wv & 1) * 64;
  const int ln15 = lane & 15;
  const int kq = (lane >> 4) * 8;
  const int sr = t >> 2;
  const int sc = (t & 3) * 8;
  const short* Ag = (const short*)A + (long)(row0 + sr) * Ks + sc;
  const short* Bg = (const short*)Bt + (long)(col0 + sr) * Ks + sc;
  const long rstep = (long)64 * Ks;

  f4v acc[4][4];
#pragma unroll
  for (int i = 0; i < 4; ++i)
#pragma unroll
    for (int j = 0; j < 4; ++j) acc[i][j] = (f4v){0.f, 0.f, 0.f, 0.f};

  uint4 a0 = *(const uint4*)(Ag);
  uint4 a1 = *(const uint4*)(Ag + rstep);
  uint4 b0 = *(const uint4*)(Bg);
  uint4 b1 = *(const uint4*)(Bg + rstep);
  for (int k0 = 0; k0 < Ks; k0 += 32) {
    __syncthreads();
    *(uint4*)&As[sr * 32 + sc] = a0;
    *(uint4*)&As[(sr + 64) * 32 + sc] = a1;
    *(uint4*)&Bs[sr * 32 + sc] = b0;
    *(uint4*)&Bs[(sr + 64) * 32 + sc] = b1;
    __syncthreads();
    if (k0 + 32 < Ks) {
      a0 = *(const uint4*)(Ag + k0 + 32);
      a1 = *(const uint4*)(Ag + rstep + k0 + 32);
      b0 = *(const uint4*)(Bg + k0 + 32);
      b1 = *(const uint4*)(Bg + rstep + k0 + 32);
    }
    s8v af[4], bf[4];
#pragma unroll
    for (int mt = 0; mt < 4; ++mt)
      af[mt] = *(const s8v*)&As[(mq + mt * 16 + ln15) * 32 + kq];
#pragma unroll
    for (int nt = 0; nt < 4; ++nt)
      bf[nt] = *(const s8v*)&Bs[(nq + nt * 16 + ln15) * 32 + kq];
#pragma unroll
    for (int mt = 0; mt < 4; ++mt)
#pragma unroll
      for (int nt = 0; nt < 4; ++nt)
        acc[mt][nt] = __builtin_amdgcn_mfma_f32_16x16x32_bf16(af[mt], bf[nt], acc[mt][nt], 0, 0, 0);
  }
  const int rbase = (lane >> 4) * 4;
#pragma unroll
  for (int mt = 0; mt < 4; ++mt) {
#pragma unroll
    for (int nt = 0; nt < 4; ++nt) {
      int gcol = col0 + nq + nt * 16 + ln15;
#pragma unroll
      for (int r = 0; r < 4; ++r) {
        int grow = row0 + mq + mt * 16 + rbase + r;
        float v = acc[mt][nt][r];
        if (ACT == 1) {
          v += bias[gcol];
          v = 0.5f * v * (1.0f + erff(v * 0.70710678118654752f));
        }
        if (BF16OUT) {
          ((__hip_bfloat16*)Cv)[(long)grow * N + gcol] = __float2bfloat16(v);
        } else {
          ((float*)Cv)[(long)grow * N + gcol] = v;
        }
      }
    }
  }
}

/* ---------- beta = sigmoid(x@Wb), idsc = 0.06 + sig(alpha)*sig(x@Wid + bid) ---------- */
__global__ __launch_bounds__(256) void rowdot8(
    const float* __restrict__ x, const float* __restrict__ Wb,
    const float* __restrict__ Wid, const float* __restrict__ alpha_id,
    const float* __restrict__ bidp, float* __restrict__ beta, float* __restrict__ idsc) {
  const int row = blockIdx.x;
  const int t = threadIdx.x;
  const float* xr = x + (long)row * DMODEL;
  float ab[4] = {0, 0, 0, 0}, ai[4] = {0, 0, 0, 0};
  for (int k = t; k < DMODEL; k += 256) {
    float xv = xr[k];
    float4 wb = *(const float4*)(Wb + k * 4);
    float4 wi = *(const float4*)(Wid + k * 4);
    ab[0] = fmaf(xv, wb.x, ab[0]); ab[1] = fmaf(xv, wb.y, ab[1]);
    ab[2] = fmaf(xv, wb.z, ab[2]); ab[3] = fmaf(xv, wb.w, ab[3]);
    ai[0] = fmaf(xv, wi.x, ai[0]); ai[1] = fmaf(xv, wi.y, ai[1]);
    ai[2] = fmaf(xv, wi.z, ai[2]); ai[3] = fmaf(xv, wi.w, ai[3]);
  }
#pragma unroll
  for (int m = 1; m < 64; m <<= 1) {
#pragma unroll
    for (int hh = 0; hh < 4; ++hh) {
      ab[hh] += __shfl_xor(ab[hh], m);
      ai[hh] += __shfl_xor(ai[hh], m);
    }
  }
  __shared__ float red[4][8];
  if ((t & 63) == 0) {
    int wv = t >> 6;
#pragma unroll
    for (int hh = 0; hh < 4; ++hh) {
      red[wv][hh] = ab[hh];
      red[wv][4 + hh] = ai[hh];
    }
  }
  __syncthreads();
  if (t < 8) {
    float s = red[0][t] + red[1][t] + red[2][t] + red[3][t];
    if (t < 4) {
      beta[(long)row * NH + t] = sigm(s);
    } else {
      int hh = t - 4;
      idsc[(long)row * NH + hh] = 0.06f + sigm(alpha_id[hh]) * sigm(s + bidp[hh]);
    }
  }
}

/* ---------- causal depthwise conv (K=4) + silu, single plane ---------- */
__global__ __launch_bounds__(256) void conv_silu(
    const float* __restrict__ pre, const float* __restrict__ cw, float* __restrict__ out) {
  const int row = blockIdx.x;
  const int l = row & (SEQ - 1);
  const int t = threadIdx.x;
  const int cb = t * 4;
  float wts[4][4];
#pragma unroll
  for (int cc = 0; cc < 4; ++cc) {
    float4 w4 = *(const float4*)(cw + (cb + cc) * 4);
    wts[cc][0] = w4.x; wts[cc][1] = w4.y; wts[cc][2] = w4.z; wts[cc][3] = w4.w;
  }
  float acc[4] = {0, 0, 0, 0};
#pragma unroll
  for (int tap = 0; tap < 4; ++tap) {
    int lr = l - 3 + tap;
    if (lr >= 0) {
      float4 xv = *(const float4*)(pre + (long)(row - 3 + tap) * DMODEL + cb);
      acc[0] = fmaf(wts[0][tap], xv.x, acc[0]);
      acc[1] = fmaf(wts[1][tap], xv.y, acc[1]);
      acc[2] = fmaf(wts[2][tap], xv.z, acc[2]);
      acc[3] = fmaf(wts[3][tap], xv.w, acc[3]);
    }
  }
  float4 ov = make_float4(siluf(acc[0]), siluf(acc[1]), siluf(acc[2]), siluf(acc[3]));
  *(float4*)(out + (long)row * DMODEL + cb) = ov;
}

/* ---------- in-place l2norm of q,k + PACKED bf16 q copy [bh][l][256] ---------- */
__global__ __launch_bounds__(256) void l2norm_qk(
    float* __restrict__ q, float* __restrict__ k, __hip_bfloat16* __restrict__ qpk) {
  const int t = threadIdx.x;
  const int unit = blockIdx.x * 4 + (t >> 6);
  const int lane = t & 63;
  const int row = unit >> 2;
  const int h = unit & 3;
  const int b = row >> 12;
  const int l = row & (SEQ - 1);
  const long base = (long)row * DMODEL + h * DHEAD + lane * 4;
  float4 q4 = *(const float4*)(q + base);
  float4 k4 = *(const float4*)(k + base);
  float sq = q4.x * q4.x + q4.y * q4.y + q4.z * q4.z + q4.w * q4.w;
  float sk = k4.x * k4.x + k4.y * k4.y + k4.z * k4.z + k4.w * k4.w;
#pragma unroll
  for (int m = 1; m < 64; m <<= 1) {
    sq += __shfl_xor(sq, m);
    sk += __shfl_xor(sk, m);
  }
  float rq = rsqrtf(sq + 1e-6f);
  float rk = rsqrtf(sk + 1e-6f);
  q4.x *= rq; q4.y *= rq; q4.z *= rq; q4.w *= rq;
  k4.x *= rk; k4.y *= rk; k4.z *= rk; k4.w *= rk;
  *(float4*)(q + base) = q4;
  *(float4*)(k + base) = k4;
  ushort4 qb;
  qb.x = f2b(q4.x); qb.y = f2b(q4.y); qb.z = f2b(q4.z); qb.w = f2b(q4.w);
  *(ushort4*)(qpk + ((long)(b * NH + h) * SEQ + l) * DHEAD + lane * 4) = qb;
}

/* ---------- phase A: per-chunk T solve; emits u (f32), w (bf16), kT (bf16),
   attn (bf16). block per (b,h,chunk) ---------- */
__global__ __launch_bounds__(256) void phaseA(
    const float* __restrict__ qn, const float* __restrict__ kn, const float* __restrict__ v,
    const float* __restrict__ beta, float* __restrict__ u,
    __hip_bfloat16* __restrict__ wb16, __hip_bfloat16* __restrict__ kTb16,
    __hip_bfloat16* __restrict__ attnb16) {
  __shared__ float Ks[32][256];
  __shared__ float T[32][33];
  __shared__ float bet[32];
  const int bid = blockIdx.x;
  const int c = bid & (NCHUNK - 1);
  const int h = (bid >> 7) & 3;
  const int b = bid >> 9;
  const int bh = b * NH + h;
  const int l0 = c * 32;
  const int t = threadIdx.x;
  const int wv = t >> 6;
  const int lane = t & 63;

#pragma unroll
  for (int r = 0; r < 8; ++r) {
    int idx = t + 256 * r;
    int i = idx >> 6;
    int f = (idx & 63) * 4;
    long gq = ((long)(b * SEQ + l0 + i)) * DMODEL + h * DHEAD + f;
    *(float4*)&Ks[i][f] = *(const float4*)(kn + gq);
  }
  if (t < 32) bet[t] = beta[(long)(b * SEQ + l0 + t) * NH + h];
  __syncthreads();

  /* T = strict-lower(-(kb kn^T)) */
  {
#pragma unroll
    for (int ii = 0; ii < 8; ++ii) {
      const int i = wv * 8 + ii;
      float4 a = *(const float4*)&Ks[i][lane * 4];
      float nbi = -bet[i];
      for (int j = 0; j < 32; ++j) {
        float val = 0.f;
        if (j < i) {
          float4 bb = *(const float4*)&Ks[j][lane * 4];
          float pd = a.x * bb.x + a.y * bb.y + a.z * bb.z + a.w * bb.w;
#pragma unroll
          for (int m = 1; m < 64; m <<= 1) pd += __shfl_xor(pd, m);
          val = nbi * pd;
        }
        if (lane == 0) T[i][j] = val;
      }
    }
  }
  __syncthreads();

  if (t < 32) {
    const int l = t;
    for (int i = 1; i < 32; ++i) {
      float s = 0.f;
      for (int j = 0; j < i; ++j) s = fmaf(T[i][j], T[j][l], s);
      T[i][l] += s;
    }
    for (int i = 0; i < 32; ++i) {
      float val = T[i][l] + (i == l ? 1.f : 0.f);
      T[i][l] = val * bet[l];
    }
  }
  __syncthreads();

  /* u = T' @ v (f32 out), w = T' @ kn (bf16 out) ; thread = column d */
  {
    const int d = t;
    float acc[32];
#pragma unroll
    for (int i = 0; i < 32; ++i) acc[i] = 0.f;
    for (int j = 0; j < 32; ++j) {
      float vv = v[((long)(b * SEQ + l0 + j)) * DMODEL + h * DHEAD + d];
#pragma unroll
      for (int i = 0; i < 32; ++i) acc[i] = fmaf(T[i][j], vv, acc[i]);
    }
    long ubase = ((long)bh * SEQ + l0) * DHEAD + d;
#pragma unroll
    for (int i = 0; i < 32; ++i) u[ubase + (long)i * DHEAD] = acc[i];
#pragma unroll
    for (int i = 0; i < 32; ++i) acc[i] = 0.f;
    for (int j = 0; j < 32; ++j) {
      float kv = Ks[j][d];
#pragma unroll
      for (int i = 0; i < 32; ++i) acc[i] = fmaf(T[i][j], kv, acc[i]);
    }
#pragma unroll
    for (int i = 0; i < 32; ++i) wb16[ubase + (long)i * DHEAD] = __float2bfloat16(acc[i]);
  }

  /* kT emit */
  {
    const int s = t;
    unsigned short* kb = (unsigned short*)kTb16 + ((long)bh * NCHUNK + c) * 8192 + (long)s * 32;
#pragma unroll
    for (int i4 = 0; i4 < 8; ++i4) {
      ushort4 pk;
      pk.x = f2b(Ks[i4 * 4 + 0][s]);
      pk.y = f2b(Ks[i4 * 4 + 1][s]);
      pk.z = f2b(Ks[i4 * 4 + 2][s]);
      pk.w = f2b(Ks[i4 * 4 + 3][s]);
      *(ushort4*)(kb + i4 * 4) = pk;
    }
  }

  /* attn = tril(qn kn^T) incl diag -> bf16 */
  {
    long abase = ((long)bh * NCHUNK + c) * 1024;
#pragma unroll
    for (int ii = 0; ii < 8; ++ii) {
      const int i = wv * 8 + ii;
      const float* qrow = qn + ((long)(b * SEQ + l0 + i)) * DMODEL + h * DHEAD;
      float4 a = *(const float4*)(qrow + lane * 4);
      for (int j = 0; j < 32; ++j) {
        float val = 0.f;
        if (j <= i) {
          float4 bb = *(const float4*)&Ks[j][lane * 4];
          float pd = a.x * bb.x + a.y * bb.y + a.z * bb.z + a.w * bb.w;
#pragma unroll
          for (int m = 1; m < 64; m <<= 1) pd += __shfl_xor(pd, m);
          val = pd;
        }
        if (lane == 0) attnb16[abase + i * 32 + j] = __float2bfloat16(val);
      }
    }
  }
}

/* ---------- phase B v4 (MFMA + software pipeline): 32 blocks = 8 bh x 4 DV-groups.
   S (256x64 slice) lives in 64 f32 accumulators/lane across all 128 chunks.
   Cross-chunk register prefetch: w (16 s8v), u (8 f32) issued pre-Y for c+1;
   kT (4 s8v) issued post-use. q/attn loads issued at chunk top, consumed at end.
   delta aliases u; all in-flight accesses address-disjoint (see r5 notes).
   2 barriers/chunk. 1 wave/SIMD -> ~512 VGPR budget, no spill expected. ---------- */
__global__ __launch_bounds__(256, 1) void phaseB(
    const __hip_bfloat16* __restrict__ qpk,  /* [bh][l][256] bf16 l2-normed q */
    const __hip_bfloat16* __restrict__ wb,   /* [bh][l][256] bf16 */
    const __hip_bfloat16* __restrict__ kTb,  /* [bh][c][s*32+i] bf16 */
    const __hip_bfloat16* __restrict__ attnb,/* [bh][c][i*32+j] bf16 */
    const float* __restrict__ u, float* __restrict__ delta /* == u region */) {
  __shared__ short Stb[64 * 264];
  __shared__ short U2T[64 * 40];
  const int bid = blockIdx.x;
  const int g = bid & 3;
  const int bh = bid >> 2;
  const int d0 = g * 64;
  const int t = threadIdx.x;
  const int wv = t >> 6, lane = t & 63;
  const int ln15 = lane & 15, qw = lane >> 4;
  const int kq = qw * 8, rbase = qw * 4;
  const int dv = wv * 16 + ln15;

  f4v Sacc[4][4];
#pragma unroll
  for (int mi = 0; mi < 4; ++mi)
#pragma unroll
    for (int nt = 0; nt < 4; ++nt) Sacc[mi][nt] = (f4v){0.f, 0.f, 0.f, 0.f};

  const short* wbase = (const short*)wb + (long)bh * SEQ * 256;
  const short* qbase = (const short*)qpk + (long)bh * SEQ * 256;
  const short* kTbase = (const short*)kTb + (long)bh * NCHUNK * 8192;
  const short* atbase = (const short*)attnb + (long)bh * NCHUNK * 1024;
  const float* ubase = u + (long)bh * SEQ * 256;
  float* dbase = delta + (long)bh * SEQ * 256;

  /* prefetch chunk 0 operands */
  s8v wpf0[8], wpf1[8], kpf[4];
  float upf0[4], upf1[4];
  {
    const short* wr0 = wbase + (long)ln15 * 256 + kq;
    const short* wr1 = wbase + (long)(16 + ln15) * 256 + kq;
#pragma unroll
    for (int ks = 0; ks < 8; ++ks) {
      wpf0[ks] = *(const s8v*)(wr0 + ks * 32);
      wpf1[ks] = *(const s8v*)(wr1 + ks * 32);
    }
#pragma unroll
    for (int mi = 0; mi < 4; ++mi)
      kpf[mi] = *(const s8v*)(kTbase + ((wv * 4 + mi) * 16 + ln15) * 32 + kq);
#pragma unroll
    for (int r = 0; r < 4; ++r) {
      upf0[r] = ubase[(long)(rbase + r) * 256 + d0 + dv];
      upf1[r] = ubase[(long)(16 + rbase + r) * 256 + d0 + dv];
    }
  }

  for (int c = 0; c < NCHUNK; ++c) {
    const int l0 = c * 32;
    /* (1) S -> Stb bf16 [dv][s] */
#pragma unroll
    for (int mi = 0; mi < 4; ++mi) {
      const int s0 = wv * 64 + mi * 16 + rbase;
#pragma unroll
      for (int nt = 0; nt < 4; ++nt) {
        ushort4 pk;
        pk.x = f2b(Sacc[mi][nt][0]);
        pk.y = f2b(Sacc[mi][nt][1]);
        pk.z = f2b(Sacc[mi][nt][2]);
        pk.w = f2b(Sacc[mi][nt][3]);
        *(ushort4*)&Stb[(nt * 16 + ln15) * 264 + s0] = pk;
      }
    }
    __syncthreads(); /* X */
    s8v bfr[8];
#pragma unroll
    for (int ks = 0; ks < 8; ++ks)
      bfr[ks] = *(const s8v*)&Stb[(wv * 16 + ln15) * 264 + ks * 32 + kq];
    /* issue q + attn loads now; consumed after Y (latency hidden under recurrence) */
    s8v qa0[8], qa1[8], at0, at1;
    {
      const short* qr0 = qbase + (long)(l0 + ln15) * 256 + kq;
      const short* qr1 = qbase + (long)(l0 + 16 + ln15) * 256 + kq;
#pragma unroll
      for (int ks = 0; ks < 8; ++ks) {
        qa0[ks] = *(const s8v*)(qr0 + ks * 32);
        qa1[ks] = *(const s8v*)(qr1 + ks * 32);
      }
      at0 = *(const s8v*)(atbase + (long)c * 1024 + ln15 * 32 + kq);
      at1 = *(const s8v*)(atbase + (long)c * 1024 + (16 + ln15) * 32 + kq);
    }
    /* (2) w@S with split chains (depth 4) */
    f4v dwA0 = (f4v){0.f, 0.f, 0.f, 0.f}, dwB0 = (f4v){0.f, 0.f, 0.f, 0.f};
    f4v dwA1 = (f4v){0.f, 0.f, 0.f, 0.f}, dwB1 = (f4v){0.f, 0.f, 0.f, 0.f};
#pragma unroll
    for (int ks = 0; ks < 4; ++ks) {
      dwA0 = __builtin_amdgcn_mfma_f32_16x16x32_bf16(wpf0[ks], bfr[ks], dwA0, 0, 0, 0);
      dwA1 = __builtin_amdgcn_mfma_f32_16x16x32_bf16(wpf1[ks], bfr[ks], dwA1, 0, 0, 0);
      dwB0 = __builtin_amdgcn_mfma_f32_16x16x32_bf16(wpf0[ks + 4], bfr[ks + 4], dwB0, 0, 0, 0);
      dwB1 = __builtin_amdgcn_mfma_f32_16x16x32_bf16(wpf1[ks + 4], bfr[ks + 4], dwB1, 0, 0, 0);
    }
    /* u2 = u - w@S, stash bf16 transposed */
    float u2a[4], u2b[4];
#pragma unroll
    for (int r = 0; r < 4; ++r) {
      u2a[r] = upf0[r] - (dwA0[r] + dwB0[r]);
      u2b[r] = upf1[r] - (dwA1[r] + dwB1[r]);
    }
    {
      ushort4 pa, pb;
      pa.x = f2b(u2a[0]); pa.y = f2b(u2a[1]); pa.z = f2b(u2a[2]); pa.w = f2b(u2a[3]);
      pb.x = f2b(u2b[0]); pb.y = f2b(u2b[1]); pb.z = f2b(u2b[2]); pb.w = f2b(u2b[3]);
      *(ushort4*)&U2T[dv * 40 + rbase] = pa;
      *(ushort4*)&U2T[dv * 40 + 16 + rbase] = pb;
    }
    /* prefetch w,u for c+1 (registers free: consumed above) */
    if (c + 1 < NCHUNK) {
      const short* nw0 = wbase + (long)(l0 + 32 + ln15) * 256 + kq;
      const short* nw1 = wbase + (long)(l0 + 48 + ln15) * 256 + kq;
#pragma unroll
      for (int ks = 0; ks < 8; ++ks) {
        wpf0[ks] = *(const s8v*)(nw0 + ks * 32);
        wpf1[ks] = *(const s8v*)(nw1 + ks * 32);
      }
#pragma unroll
      for (int r = 0; r < 4; ++r) {
        upf0[r] = ubase[(long)(l0 + 32 + rbase + r) * 256 + d0 + dv];
        upf1[r] = ubase[(long)(l0 + 48 + rbase + r) * 256 + d0 + dv];
      }
    }
    __syncthreads(); /* Y */
    /* (3) recurrence: S += kT@u2 */
    s8v bu[4];
#pragma unroll
    for (int nt = 0; nt < 4; ++nt)
      bu[nt] = *(const s8v*)&U2T[(nt * 16 + ln15) * 40 + kq];
#pragma unroll
    for (int mi = 0; mi < 4; ++mi)
#pragma unroll
      for (int nt = 0; nt < 4; ++nt)
        Sacc[mi][nt] = __builtin_amdgcn_mfma_f32_16x16x32_bf16(kpf[mi], bu[nt], Sacc[mi][nt], 0, 0, 0);
    /* prefetch kT for c+1 (after use) */
    if (c + 1 < NCHUNK) {
#pragma unroll
      for (int mi = 0; mi < 4; ++mi)
        kpf[mi] = *(const s8v*)(kTbase + (long)(c + 1) * 8192 + ((wv * 4 + mi) * 16 + ln15) * 32 + kq);
    }
    /* (4) output path: o = q@S + attn@u2 (bfr regs still hold S_c) */
    f4v oA0 = (f4v){0.f, 0.f, 0.f, 0.f}, oB0 = (f4v){0.f, 0.f, 0.f, 0.f};
    f4v oA1 = (f4v){0.f, 0.f, 0.f, 0.f}, oB1 = (f4v){0.f, 0.f, 0.f, 0.f};
#pragma unroll
    for (int ks = 0; ks < 4; ++ks) {
      oA0 = __builtin_amdgcn_mfma_f32_16x16x32_bf16(qa0[ks], bfr[ks], oA0, 0, 0, 0);
      oA1 = __builtin_amdgcn_mfma_f32_16x16x32_bf16(qa1[ks], bfr[ks], oA1, 0, 0, 0);
      oB0 = __builtin_amdgcn_mfma_f32_16x16x32_bf16(qa0[ks + 4], bfr[ks + 4], oB0, 0, 0, 0);
      oB1 = __builtin_amdgcn_mfma_f32_16x16x32_bf16(qa1[ks + 4], bfr[ks + 4], oB1, 0, 0, 0);
    }
    oA0 = __builtin_amdgcn_mfma_f32_16x16x32_bf16(at0, bu[wv], oA0, 0, 0, 0);
    oA1 = __builtin_amdgcn_mfma_f32_16x16x32_bf16(at1, bu[wv], oA1, 0, 0, 0);
#pragma unroll
    for (int r = 0; r < 4; ++r) {
      dbase[(long)(l0 + rbase + r) * 256 + d0 + dv] = oA0[r] + oB0[r];
      dbase[(long)(l0 + 16 + rbase + r) * 256 + d0 + dv] = oA1[r] + oB1[r];
    }
    /* no tail barrier: next X orders Stb/U2T reuse */
  }
}

/* ---------- FIR short(3)+long(31) causal depthwise convs on vh ---------- */
__global__ __launch_bounds__(256) void fir_kernel(
    const float* __restrict__ v, const float* __restrict__ fshort,
    const float* __restrict__ flong, float* __restrict__ fs, float* __restrict__ fl) {
  const int row = blockIdx.x;
  const int l = row & (SEQ - 1);
  const int t = threadIdx.x;
  const int cb = t * 4;
  float4 accl = make_float4(0, 0, 0, 0);
  float4 accs = make_float4(0, 0, 0, 0);
  for (int j = 0; j < 31; ++j) {
    int lr = l - 30 + j;
    if (lr < 0) continue;
    float4 xv = *(const float4*)(v + (long)(row - 30 + j) * DMODEL + cb);
    float w0 = flong[(cb + 0) * 31 + j];
    float w1 = flong[(cb + 1) * 31 + j];
    float w2 = flong[(cb + 2) * 31 + j];
    float w3 = flong[(cb + 3) * 31 + j];
    accl.x = fmaf(w0, xv.x, accl.x);
    accl.y = fmaf(w1, xv.y, accl.y);
    accl.z = fmaf(w2, xv.z, accl.z);
    accl.w = fmaf(w3, xv.w, accl.w);
    if (j >= 28) {
      int tp = j - 28;
      float s0 = fshort[(cb + 0) * 3 + tp];
      float s1 = fshort[(cb + 1) * 3 + tp];
      float s2 = fshort[(cb + 2) * 3 + tp];
      float s3 = fshort[(cb + 3) * 3 + tp];
      accs.x = fmaf(s0, xv.x, accs.x);
      accs.y = fmaf(s1, xv.y, accs.y);
      accs.z = fmaf(s2, xv.z, accs.z);
      accs.w = fmaf(s3, xv.w, accs.w);
    }
  }
  *(float4*)(fs + (long)row * DMODEL + cb) = accs;
  *(float4*)(fl + (long)row * DMODEL + cb) = accl;
}

/* ---------- stats + assemble router input as bf16 (stride 1056, zero pad) ---------- */
__global__ __launch_bounds__(256) void stats_router(
    const float* __restrict__ x, const float* __restrict__ fs,
    const float* __restrict__ fl, const float* __restrict__ dl,
    __hip_bfloat16* __restrict__ rinb) {
  const int row = blockIdx.x;
  const int b = row >> 12;
  const int l = row & (SEQ - 1);
  const int t = threadIdx.x;
  float4 xv = *(const float4*)(x + (long)row * DMODEL + t * 4);
  {
    __hip_bfloat16 tmp[4] = {__float2bfloat16(xv.x), __float2bfloat16(xv.y),
                             __float2bfloat16(xv.z), __float2bfloat16(xv.w)};
    *(ushort4*)(rinb + (long)row * 1056 + t * 4) = *(ushort4*)tmp;
  }
  if (t < 8) rinb[(long)row * 1056 + 1048 + t] = __float2bfloat16(0.f);
  const int h = t >> 6;
  const int lane = t & 63;
  const long base = (long)row * DMODEL + h * DHEAD + lane * 4;
  const long dbase = ((long)(b * NH + h) * SEQ + l) * DHEAD + lane * 4;
  float4 a = *(const float4*)(fs + base);
  float4 bq = *(const float4*)(fl + base);
  float4 cq = *(const float4*)(dl + dbase);
  float s[6];
  s[0] = a.x + a.y + a.z + a.w;
  s[1] = a.x * a.x + a.y * a.y + a.z * a.z + a.w * a.w;
  s[2] = bq.x + bq.y + bq.z + bq.w;
  s[3] = bq.x * bq.x + bq.y * bq.y + bq.z * bq.z + bq.w * bq.w;
  s[4] = cq.x + cq.y + cq.z + cq.w;
  s[5] = cq.x * cq.x + cq.y * cq.y + cq.z * cq.z + cq.w * cq.w;
#pragma unroll
  for (int m = 1; m < 64; m <<= 1)
#pragma unroll
    for (int j = 0; j < 6; ++j) s[j] += __shfl_xor(s[j], m);
  if (lane == 0) {
    __hip_bfloat16* rb = rinb + (long)row * 1056 + 1024;
    float m0 = s[0] * (1.f / 256.f);
    float m1 = s[2] * (1.f / 256.f);
    float m2 = s[4] * (1.f / 256.f);
    rb[h] = __float2bfloat16(m0);
    rb[4 + h] = __float2bfloat16(sqrtf(fmaxf(s[1] * (1.f / 256.f) - m0 * m0, 0.f)));
    rb[8 + h] = __float2bfloat16(m1);
    rb[12 + h] = __float2bfloat16(sqrtf(fmaxf(s[3] * (1.f / 256.f) - m1 * m1, 0.f)));
    rb[16 + h] = __float2bfloat16(m2);
    rb[20 + h] = __float2bfloat16(sqrtf(fmaxf(s[5] * (1.f / 256.f) - m2 * m2, 0.f)));
  }
}

/* ---------- logits from bf16 hmid ; p = softmax(logits/tau)*0.925+0.025 ---------- */
__global__ __launch_bounds__(256) void router_logits(
    const __hip_bfloat16* __restrict__ hmid, const float* __restrict__ Wr2,
    const float* __restrict__ br2, const float* __restrict__ ltg, float* __restrict__ p) {
  const int row = blockIdx.x;
  const int t = threadIdx.x;
  float acc[12];
#pragma unroll
  for (int j = 0; j < 12; ++j) acc[j] = 0.f;
  const __hip_bfloat16* hr = hmid + (long)row * 2048;
  for (int k = t; k < 2048; k += 256) {
    float hv = __bfloat162float(hr[k]);
    const float* wr = Wr2 + k * 12;
#pragma unroll
    for (int j = 0; j < 12; ++j) acc[j] = fmaf(hv, wr[j], acc[j]);
  }
#pragma unroll
  for (int m = 1; m < 64; m <<= 1)
#pragma unroll
    for (int j = 0; j < 12; ++j) acc[j] += __shfl_xor(acc[j], m);
  __shared__ float red[4][12];
  if ((t & 63) == 0) {
    int wv = t >> 6;
#pragma unroll
    for (int j = 0; j < 12; ++j) red[wv][j] = acc[j];
  }
  __syncthreads();
  if (t < 4) {
    const int h = t;
    float l3[3];
#pragma unroll
    for (int j = 0; j < 3; ++j) {
      int col = h * 3 + j;
      l3[j] = red[0][col] + red[1][col] + red[2][col] + red[3][col] + br2[col];
    }
    float inv_tau = expf(-ltg[h >> 1]);
    float y0 = l3[0] * inv_tau, y1 = l3[1] * inv_tau, y2 = l3[2] * inv_tau;
    float mx = fmaxf(y0, fmaxf(y1, y2));
    float e0 = expf(y0 - mx), e1 = expf(y1 - mx), e2 = expf(y2 - mx);
    float inv = 1.f / (e0 + e1 + e2);
    p[(long)row * 12 + h * 3 + 0] = e0 * inv * 0.925f + 0.025f;
    p[(long)row * 12 + h * 3 + 1] = e1 * inv * 0.925f + 0.025f;
    p[(long)row * 12 + h * 3 + 2] = e2 * inv * 0.925f + 0.025f;
  }
}

/* ---------- mixture + identity + RMS norm -> bf16 out. delta layout (B,H,L,DV). ---------- */
__global__ __launch_bounds__(256) void omix(
    const float* __restrict__ fs, const float* __restrict__ fl,
    const float* __restrict__ dl, const float* __restrict__ vh,
    const float* __restrict__ p, const float* __restrict__ idsc,
    const float* __restrict__ onw, __hip_bfloat16* __restrict__ o) {
  const int row = blockIdx.x;
  const int b = row >> 12;
  const int l = row & (SEQ - 1);
  const int t = threadIdx.x;
  const int h = t >> 6;
  const int lane = t & 63;
  const long base = (long)row * DMODEL + h * DHEAD + lane * 4;
  const long dbase = ((long)(b * NH + h) * SEQ + l) * DHEAD + lane * 4;
  float p0 = p[(long)row * 12 + h * 3 + 0];
  float p1 = p[(long)row * 12 + h * 3 + 1];
  float p2 = p[(long)row * 12 + h * 3 + 2];
  float idv = idsc[(long)row * NH + h];
  float4 a = *(const float4*)(fs + base);
  float4 bq = *(const float4*)(fl + base);
  float4 cq = *(const float4*)(dl + dbase);
  float4 vv = *(const float4*)(vh + base);
  float4 ov;
  ov.x = p0 * a.x + p1 * bq.x + p2 * cq.x + idv * vv.x;
  ov.y = p0 * a.y + p1 * bq.y + p2 * cq.y + idv * vv.y;
  ov.z = p0 * a.z + p1 * bq.z + p2 * cq.z + idv * vv.z;
  ov.w = p0 * a.w + p1 * bq.w + p2 * cq.w + idv * vv.w;
  float ss = ov.x * ov.x + ov.y * ov.y + ov.z * ov.z + ov.w * ov.w;
#pragma unroll
  for (int m = 1; m < 64; m <<= 1) ss += __shfl_xor(ss, m);
  float rms = rsqrtf(ss * (1.f / 256.f) + 1e-5f);
  float4 wn = *(const float4*)(onw + lane * 4);
  __hip_bfloat16 tmp[4] = {__float2bfloat16(ov.x * rms * wn.x),
                           __float2bfloat16(ov.y * rms * wn.y),
                           __float2bfloat16(ov.z * rms * wn.z),
                           __float2bfloat16(ov.w * rms * wn.w)};
  *(ushort4*)(o + base) = *(ushort4*)tmp;
}

extern "C" void kernel_launch(void* const* d_in, const int* in_sizes, int n_in,
                              void* d_out, int out_size, void* d_ws, size_t ws_size,
                              hipStream_t stream) {
  const float* x = (const float*)d_in[0];
  const float* Wq = (const float*)d_in[1];
  const float* Wk = (const float*)d_in[2];
  const float* Wv = (const float*)d_in[3];
  const float* Wb = (const float*)d_in[4];
  const float* conv_q = (const float*)d_in[5];
  const float* conv_k = (const float*)d_in[6];
  const float* conv_v = (const float*)d_in[7];
  const float* fir_s = (const float*)d_in[8];
  const float* fir_l = (const float*)d_in[9];
  const float* alpha_id = (const float*)d_in[10];
  const float* Wid = (const float*)d_in[11];
  const float* bidp = (const float*)d_in[12];
  const float* Wr1 = (const float*)d_in[13];
  const float* br1 = (const float*)d_in[14];
  const float* Wr2 = (const float*)d_in[15];
  const float* br2 = (const float*)d_in[16];
  const float* ltg = (const float*)d_in[17];
  const float* onw = (const float*)d_in[19];
  const float* Wo = (const float*)d_in[20];

  /* workspace layout identical to round 4 (qb16 region now holds PACKED q) */
  float* ws = (float*)d_ws;
  float* pre = ws + 0;
  float* ubuf = ws + 8388608;
  float* wbuf = ws + 16777216;
  float* attnbuf = ws + 25165824;
  float* qbuf = ws + 26214400;
  float* kbuf = ws + 34603008;
  float* vbuf = ws + 42991616;
  float* betabuf = ws + 51380224;
  float* idscbuf = ws + 51412992;
  float* pbuf = ws + 51445760;
  float* deltabuf = ubuf;
  __hip_bfloat16* xb = (__hip_bfloat16*)ubuf;
  __hip_bfloat16* Wqt = (__hip_bfloat16*)(wbuf);
  __hip_bfloat16* Wkt = (__hip_bfloat16*)(wbuf + 524288);
  __hip_bfloat16* Wvt = (__hip_bfloat16*)(wbuf + 1048576);
  __hip_bfloat16* wb16 = (__hip_bfloat16*)wbuf;
  __hip_bfloat16* kTb16 = (__hip_bfloat16*)wbuf + 8388608;
  __hip_bfloat16* attnb16 = (__hip_bfloat16*)attnbuf;
  __hip_bfloat16* qpk16 = (__hip_bfloat16*)pre;
  __hip_bfloat16* rinb = (__hip_bfloat16*)(wbuf);
  __hip_bfloat16* Wr1t = (__hip_bfloat16*)(wbuf + 4325376);
  __hip_bfloat16* Wot = (__hip_bfloat16*)(wbuf + 5406720);
  __hip_bfloat16* omixb = (__hip_bfloat16*)(wbuf);
  __hip_bfloat16* hmid = (__hip_bfloat16*)pre;
  float* fsb = qbuf;
  float* flb = kbuf;

  dim3 blk(256);
  cast_bf16<<<dim3(ROWS), blk, 0, stream>>>(x, xb);
  transpose_cast<<<dim3(32, 32), blk, 0, stream>>>(Wq, Wqt, 1024, 1024, 1024);
  transpose_cast<<<dim3(32, 32), blk, 0, stream>>>(Wk, Wkt, 1024, 1024, 1024);
  transpose_cast<<<dim3(32, 32), blk, 0, stream>>>(Wv, Wvt, 1024, 1024, 1024);
  gemm_bf16<0, false><<<dim3(8, 64), blk, 0, stream>>>(xb, Wqt, nullptr, pre, ROWS, 1024, 1024);
  conv_silu<<<dim3(ROWS), blk, 0, stream>>>(pre, conv_q, qbuf);
  gemm_bf16<0, false><<<dim3(8, 64), blk, 0, stream>>>(xb, Wkt, nullptr, pre, ROWS, 1024, 1024);
  conv_silu<<<dim3(ROWS), blk, 0, stream>>>(pre, conv_k, kbuf);
  gemm_bf16<0, false><<<dim3(8, 64), blk, 0, stream>>>(xb, Wvt, nullptr, pre, ROWS, 1024, 1024);
  conv_silu<<<dim3(ROWS), blk, 0, stream>>>(pre, conv_v, vbuf);
  rowdot8<<<dim3(ROWS), blk, 0, stream>>>(x, Wb, Wid, alpha_id, bidp, betabuf, idscbuf);
  l2norm_qk<<<dim3(ROWS), blk, 0, stream>>>(qbuf, kbuf, qpk16);
  phaseA<<<dim3(BATCH * NH * NCHUNK), blk, 0, stream>>>(qbuf, kbuf, vbuf, betabuf, ubuf, wb16, kTb16, attnb16);
  phaseB<<<dim3(BATCH * NH * 4), blk, 0, stream>>>(qpk16, wb16, kTb16, attnb16, ubuf, deltabuf);
  fir_kernel<<<dim3(ROWS), blk, 0, stream>>>(vbuf, fir_s, fir_l, fsb, flb);
  stats_router<<<dim3(ROWS), blk, 0, stream>>>(x, fsb, flb, deltabuf, rinb);
  transpose_cast<<<dim3(64, 33), blk, 0, stream>>>(Wr1, Wr1t, 1048, 2048, 1056);
  transpose_cast<<<dim3(32, 32), blk, 0, stream>>>(Wo, Wot, 1024, 1024, 1024);
  gemm_bf16<1, true><<<dim3(16, 64), blk, 0, stream>>>(rinb, Wr1t, br1, hmid, ROWS, 2048, 1056);
  router_logits<<<dim3(ROWS), blk, 0, stream>>>(hmid, Wr2, br2, ltg, pbuf);
  omix<<<dim3(ROWS), blk, 0, stream>>>(fsb, flb, deltabuf, vbuf, pbuf, idscbuf, onw, omixb);
  gemm_bf16<0, false><<<dim3(8, 64), blk, 0, stream>>>(omixb, Wot, nullptr, d_out, ROWS, 1024, 1024);
}

// Round 6
// 1587.655 us; speedup vs baseline: 2.5179x; 1.5657x over previous
//
#include <hip/hip_runtime.h>
#include <hip/hip_bf16.h>
#include <math.h>

#define BATCH 2
#define SEQ 4096
#define DMODEL 1024
#define NH 4
#define DHEAD 256
#define NCHUNK 128
#define ROWS (BATCH * SEQ) /* 8192 */

typedef short s8v __attribute__((ext_vector_type(8)));   /* 8 bf16 in 4 VGPRs */
typedef float f4v __attribute__((ext_vector_type(4)));

__device__ __forceinline__ float sigm(float x) { return 1.0f / (1.0f + expf(-x)); }
__device__ __forceinline__ float siluf(float x) { return x / (1.0f + expf(-x)); }
__device__ __forceinline__ unsigned short f2b(float f) {
  __hip_bfloat16 h = __float2bfloat16(f);
  return *(unsigned short*)&h;
}

/* ---------- cast f32 -> bf16, n multiple of 1024, grid = n/1024 ---------- */
__global__ __launch_bounds__(256) void cast_bf16(
    const float* __restrict__ in, __hip_bfloat16* __restrict__ out) {
  long i = ((long)blockIdx.x * 256 + threadIdx.x) * 4;
  float4 v = *(const float4*)(in + i);
  __hip_bfloat16 tmp[4] = {__float2bfloat16(v.x), __float2bfloat16(v.y),
                           __float2bfloat16(v.z), __float2bfloat16(v.w)};
  *(ushort4*)(out + i) = *(ushort4*)tmp;
}

/* ---------- transpose K x N f32 -> N x Ks bf16 (zero-pad rows K..Ks) ---------- */
__global__ __launch_bounds__(256) void transpose_cast(
    const float* __restrict__ W, __hip_bfloat16* __restrict__ Wt,
    int K, int N, int Ks) {
  __shared__ float tile[32][33];
  const int t = threadIdx.x;
  const int tx = t & 31, ty = t >> 5;
  const int kb = blockIdx.y * 32, nb = blockIdx.x * 32;
#pragma unroll
  for (int r = 0; r < 4; ++r) {
    int kk = kb + ty + 8 * r;
    tile[ty + 8 * r][tx] = (kk < K) ? W[(long)kk * N + nb + tx] : 0.f;
  }
  __syncthreads();
#pragma unroll
  for (int r = 0; r < 4; ++r) {
    Wt[(long)(nb + ty + 8 * r) * Ks + kb + tx] = __float2bfloat16(tile[tx][ty + 8 * r]);
  }
}

/* ---------- transpose FIR filters [ch][tap] -> [tap][ch] (runs once, tiny) ---------- */
__global__ __launch_bounds__(256) void fir_transpose(
    const float* __restrict__ fshort, const float* __restrict__ flong,
    float* __restrict__ fsT, float* __restrict__ flT) {
  const int j = blockIdx.x; /* 0..30 long, 31..33 short */
  const int t = threadIdx.x;
  if (j < 31) {
#pragma unroll
    for (int i = 0; i < 4; ++i) {
      int c = t * 4 + i;
      flT[j * 1024 + c] = flong[c * 31 + j];
    }
  } else {
    int tp = j - 31;
#pragma unroll
    for (int i = 0; i < 4; ++i) {
      int c = t * 4 + i;
      fsT[tp * 1024 + c] = fshort[c * 3 + tp];
    }
  }
}

/* ---------------- bf16 MFMA GEMM: C = A(MxKs) * Bt(NxKs)^T ---------------- */
template <int ACT, bool BF16OUT>
__global__ __launch_bounds__(256) void gemm_bf16(
    const __hip_bfloat16* __restrict__ A, const __hip_bfloat16* __restrict__ Bt,
    const float* __restrict__ bias, void* __restrict__ Cv,
    int M, int N, int Ks) {
  __shared__ short As[128 * 32];
  __shared__ short Bs[128 * 32];
  const int t = threadIdx.x;
  const int wv = t >> 6;
  const int lane = t & 63;
  const int row0 = blockIdx.y * 128, col0 = blockIdx.x * 128;
  const int mq = (wv >> 1) * 64, nq = (wv & 1) * 64;
  const int ln15 = lane & 15;
  const int kq = (lane >> 4) * 8;
  const int sr = t >> 2;
  const int sc = (t & 3) * 8;
  const short* Ag = (const short*)A + (long)(row0 + sr) * Ks + sc;
  const short* Bg = (const short*)Bt + (long)(col0 + sr) * Ks + sc;
  const long rstep = (long)64 * Ks;

  f4v acc[4][4];
#pragma unroll
  for (int i = 0; i < 4; ++i)
#pragma unroll
    for (int j = 0; j < 4; ++j) acc[i][j] = (f4v){0.f, 0.f, 0.f, 0.f};

  uint4 a0 = *(const uint4*)(Ag);
  uint4 a1 = *(const uint4*)(Ag + rstep);
  uint4 b0 = *(const uint4*)(Bg);
  uint4 b1 = *(const uint4*)(Bg + rstep);
  for (int k0 = 0; k0 < Ks; k0 += 32) {
    __syncthreads();
    *(uint4*)&As[sr * 32 + sc] = a0;
    *(uint4*)&As[(sr + 64) * 32 + sc] = a1;
    *(uint4*)&Bs[sr * 32 + sc] = b0;
    *(uint4*)&Bs[(sr + 64) * 32 + sc] = b1;
    __syncthreads();
    if (k0 + 32 < Ks) {
      a0 = *(const uint4*)(Ag + k0 + 32);
      a1 = *(const uint4*)(Ag + rstep + k0 + 32);
      b0 = *(const uint4*)(Bg + k0 + 32);
      b1 = *(const uint4*)(Bg + rstep + k0 + 32);
    }
    s8v af[4], bf[4];
#pragma unroll
    for (int mt = 0; mt < 4; ++mt)
      af[mt] = *(const s8v*)&As[(mq + mt * 16 + ln15) * 32 + kq];
#pragma unroll
    for (int nt = 0; nt < 4; ++nt)
      bf[nt] = *(const s8v*)&Bs[(nq + nt * 16 + ln15) * 32 + kq];
#pragma unroll
    for (int mt = 0; mt < 4; ++mt)
#pragma unroll
      for (int nt = 0; nt < 4; ++nt)
        acc[mt][nt] = __builtin_amdgcn_mfma_f32_16x16x32_bf16(af[mt], bf[nt], acc[mt][nt], 0, 0, 0);
  }
  const int rbase = (lane >> 4) * 4;
#pragma unroll
  for (int mt = 0; mt < 4; ++mt) {
#pragma unroll
    for (int nt = 0; nt < 4; ++nt) {
      int gcol = col0 + nq + nt * 16 + ln15;
#pragma unroll
      for (int r = 0; r < 4; ++r) {
        int grow = row0 + mq + mt * 16 + rbase + r;
        float v = acc[mt][nt][r];
        if (ACT == 1) {
          v += bias[gcol];
          v = 0.5f * v * (1.0f + erff(v * 0.70710678118654752f));
        }
        if (BF16OUT) {
          ((__hip_bfloat16*)Cv)[(long)grow * N + gcol] = __float2bfloat16(v);
        } else {
          ((float*)Cv)[(long)grow * N + gcol] = v;
        }
      }
    }
  }
}

/* ---------- beta = sigmoid(x@Wb), idsc = 0.06 + sig(alpha)*sig(x@Wid + bid) ---------- */
__global__ __launch_bounds__(256) void rowdot8(
    const float* __restrict__ x, const float* __restrict__ Wb,
    const float* __restrict__ Wid, const float* __restrict__ alpha_id,
    const float* __restrict__ bidp, float* __restrict__ beta, float* __restrict__ idsc) {
  const int row = blockIdx.x;
  const int t = threadIdx.x;
  const float* xr = x + (long)row * DMODEL;
  float ab[4] = {0, 0, 0, 0}, ai[4] = {0, 0, 0, 0};
  for (int k = t; k < DMODEL; k += 256) {
    float xv = xr[k];
    float4 wb = *(const float4*)(Wb + k * 4);
    float4 wi = *(const float4*)(Wid + k * 4);
    ab[0] = fmaf(xv, wb.x, ab[0]); ab[1] = fmaf(xv, wb.y, ab[1]);
    ab[2] = fmaf(xv, wb.z, ab[2]); ab[3] = fmaf(xv, wb.w, ab[3]);
    ai[0] = fmaf(xv, wi.x, ai[0]); ai[1] = fmaf(xv, wi.y, ai[1]);
    ai[2] = fmaf(xv, wi.z, ai[2]); ai[3] = fmaf(xv, wi.w, ai[3]);
  }
#pragma unroll
  for (int m = 1; m < 64; m <<= 1) {
#pragma unroll
    for (int hh = 0; hh < 4; ++hh) {
      ab[hh] += __shfl_xor(ab[hh], m);
      ai[hh] += __shfl_xor(ai[hh], m);
    }
  }
  __shared__ float red[4][8];
  if ((t & 63) == 0) {
    int wv = t >> 6;
#pragma unroll
    for (int hh = 0; hh < 4; ++hh) {
      red[wv][hh] = ab[hh];
      red[wv][4 + hh] = ai[hh];
    }
  }
  __syncthreads();
  if (t < 8) {
    float s = red[0][t] + red[1][t] + red[2][t] + red[3][t];
    if (t < 4) {
      beta[(long)row * NH + t] = sigm(s);
    } else {
      int hh = t - 4;
      idsc[(long)row * NH + hh] = 0.06f + sigm(alpha_id[hh]) * sigm(s + bidp[hh]);
    }
  }
}

/* ---------- causal depthwise conv (K=4) + silu, single plane ---------- */
__global__ __launch_bounds__(256) void conv_silu(
    const float* __restrict__ pre, const float* __restrict__ cw, float* __restrict__ out) {
  const int row = blockIdx.x;
  const int l = row & (SEQ - 1);
  const int t = threadIdx.x;
  const int cb = t * 4;
  float wts[4][4];
#pragma unroll
  for (int cc = 0; cc < 4; ++cc) {
    float4 w4 = *(const float4*)(cw + (cb + cc) * 4);
    wts[cc][0] = w4.x; wts[cc][1] = w4.y; wts[cc][2] = w4.z; wts[cc][3] = w4.w;
  }
  float acc[4] = {0, 0, 0, 0};
#pragma unroll
  for (int tap = 0; tap < 4; ++tap) {
    int lr = l - 3 + tap;
    if (lr >= 0) {
      float4 xv = *(const float4*)(pre + (long)(row - 3 + tap) * DMODEL + cb);
      acc[0] = fmaf(wts[0][tap], xv.x, acc[0]);
      acc[1] = fmaf(wts[1][tap], xv.y, acc[1]);
      acc[2] = fmaf(wts[2][tap], xv.z, acc[2]);
      acc[3] = fmaf(wts[3][tap], xv.w, acc[3]);
    }
  }
  float4 ov = make_float4(siluf(acc[0]), siluf(acc[1]), siluf(acc[2]), siluf(acc[3]));
  *(float4*)(out + (long)row * DMODEL + cb) = ov;
}

/* ---------- in-place l2norm of q,k + PACKED bf16 q copy [bh][l][256] ---------- */
__global__ __launch_bounds__(256) void l2norm_qk(
    float* __restrict__ q, float* __restrict__ k, __hip_bfloat16* __restrict__ qpk) {
  const int t = threadIdx.x;
  const int unit = blockIdx.x * 4 + (t >> 6);
  const int lane = t & 63;
  const int row = unit >> 2;
  const int h = unit & 3;
  const int b = row >> 12;
  const int l = row & (SEQ - 1);
  const long base = (long)row * DMODEL + h * DHEAD + lane * 4;
  float4 q4 = *(const float4*)(q + base);
  float4 k4 = *(const float4*)(k + base);
  float sq = q4.x * q4.x + q4.y * q4.y + q4.z * q4.z + q4.w * q4.w;
  float sk = k4.x * k4.x + k4.y * k4.y + k4.z * k4.z + k4.w * k4.w;
#pragma unroll
  for (int m = 1; m < 64; m <<= 1) {
    sq += __shfl_xor(sq, m);
    sk += __shfl_xor(sk, m);
  }
  float rq = rsqrtf(sq + 1e-6f);
  float rk = rsqrtf(sk + 1e-6f);
  q4.x *= rq; q4.y *= rq; q4.z *= rq; q4.w *= rq;
  k4.x *= rk; k4.y *= rk; k4.z *= rk; k4.w *= rk;
  *(float4*)(q + base) = q4;
  *(float4*)(k + base) = k4;
  ushort4 qb;
  qb.x = f2b(q4.x); qb.y = f2b(q4.y); qb.z = f2b(q4.z); qb.w = f2b(q4.w);
  *(ushort4*)(qpk + ((long)(b * NH + h) * SEQ + l) * DHEAD + lane * 4) = qb;
}

/* ---------- phase A: per-chunk T solve; emits u (f32), w (bf16), kT (bf16),
   attn (bf16). block per (b,h,chunk) ---------- */
__global__ __launch_bounds__(256) void phaseA(
    const float* __restrict__ qn, const float* __restrict__ kn, const float* __restrict__ v,
    const float* __restrict__ beta, float* __restrict__ u,
    __hip_bfloat16* __restrict__ wb16, __hip_bfloat16* __restrict__ kTb16,
    __hip_bfloat16* __restrict__ attnb16) {
  __shared__ float Ks[32][256];
  __shared__ float T[32][33];
  __shared__ float bet[32];
  const int bid = blockIdx.x;
  const int c = bid & (NCHUNK - 1);
  const int h = (bid >> 7) & 3;
  const int b = bid >> 9;
  const int bh = b * NH + h;
  const int l0 = c * 32;
  const int t = threadIdx.x;
  const int wv = t >> 6;
  const int lane = t & 63;

#pragma unroll
  for (int r = 0; r < 8; ++r) {
    int idx = t + 256 * r;
    int i = idx >> 6;
    int f = (idx & 63) * 4;
    long gq = ((long)(b * SEQ + l0 + i)) * DMODEL + h * DHEAD + f;
    *(float4*)&Ks[i][f] = *(const float4*)(kn + gq);
  }
  if (t < 32) bet[t] = beta[(long)(b * SEQ + l0 + t) * NH + h];
  __syncthreads();

  /* T = strict-lower(-(kb kn^T)) */
  {
#pragma unroll
    for (int ii = 0; ii < 8; ++ii) {
      const int i = wv * 8 + ii;
      float4 a = *(const float4*)&Ks[i][lane * 4];
      float nbi = -bet[i];
      for (int j = 0; j < 32; ++j) {
        float val = 0.f;
        if (j < i) {
          float4 bb = *(const float4*)&Ks[j][lane * 4];
          float pd = a.x * bb.x + a.y * bb.y + a.z * bb.z + a.w * bb.w;
#pragma unroll
          for (int m = 1; m < 64; m <<= 1) pd += __shfl_xor(pd, m);
          val = nbi * pd;
        }
        if (lane == 0) T[i][j] = val;
      }
    }
  }
  __syncthreads();

  if (t < 32) {
    const int l = t;
    for (int i = 1; i < 32; ++i) {
      float s = 0.f;
      for (int j = 0; j < i; ++j) s = fmaf(T[i][j], T[j][l], s);
      T[i][l] += s;
    }
    for (int i = 0; i < 32; ++i) {
      float val = T[i][l] + (i == l ? 1.f : 0.f);
      T[i][l] = val * bet[l];
    }
  }
  __syncthreads();

  /* u = T' @ v (f32 out), w = T' @ kn (bf16 out) ; thread = column d */
  {
    const int d = t;
    float acc[32];
#pragma unroll
    for (int i = 0; i < 32; ++i) acc[i] = 0.f;
    for (int j = 0; j < 32; ++j) {
      float vv = v[((long)(b * SEQ + l0 + j)) * DMODEL + h * DHEAD + d];
#pragma unroll
      for (int i = 0; i < 32; ++i) acc[i] = fmaf(T[i][j], vv, acc[i]);
    }
    long ubase = ((long)bh * SEQ + l0) * DHEAD + d;
#pragma unroll
    for (int i = 0; i < 32; ++i) u[ubase + (long)i * DHEAD] = acc[i];
#pragma unroll
    for (int i = 0; i < 32; ++i) acc[i] = 0.f;
    for (int j = 0; j < 32; ++j) {
      float kv = Ks[j][d];
#pragma unroll
      for (int i = 0; i < 32; ++i) acc[i] = fmaf(T[i][j], kv, acc[i]);
    }
#pragma unroll
    for (int i = 0; i < 32; ++i) wb16[ubase + (long)i * DHEAD] = __float2bfloat16(acc[i]);
  }

  /* kT emit */
  {
    const int s = t;
    unsigned short* kb = (unsigned short*)kTb16 + ((long)bh * NCHUNK + c) * 8192 + (long)s * 32;
#pragma unroll
    for (int i4 = 0; i4 < 8; ++i4) {
      ushort4 pk;
      pk.x = f2b(Ks[i4 * 4 + 0][s]);
      pk.y = f2b(Ks[i4 * 4 + 1][s]);
      pk.z = f2b(Ks[i4 * 4 + 2][s]);
      pk.w = f2b(Ks[i4 * 4 + 3][s]);
      *(ushort4*)(kb + i4 * 4) = pk;
    }
  }

  /* attn = tril(qn kn^T) incl diag -> bf16 */
  {
    long abase = ((long)bh * NCHUNK + c) * 1024;
#pragma unroll
    for (int ii = 0; ii < 8; ++ii) {
      const int i = wv * 8 + ii;
      const float* qrow = qn + ((long)(b * SEQ + l0 + i)) * DMODEL + h * DHEAD;
      float4 a = *(const float4*)(qrow + lane * 4);
      for (int j = 0; j < 32; ++j) {
        float val = 0.f;
        if (j <= i) {
          float4 bb = *(const float4*)&Ks[j][lane * 4];
          float pd = a.x * bb.x + a.y * bb.y + a.z * bb.z + a.w * bb.w;
#pragma unroll
          for (int m = 1; m < 64; m <<= 1) pd += __shfl_xor(pd, m);
          val = pd;
        }
        if (lane == 0) attnb16[abase + i * 32 + j] = __float2bfloat16(val);
      }
    }
  }
}

/* ---------- phase B v4 (MFMA + software pipeline): 32 blocks = 8 bh x 4 DV-groups. ---------- */
__global__ __launch_bounds__(256, 1) void phaseB(
    const __hip_bfloat16* __restrict__ qpk,  /* [bh][l][256] bf16 l2-normed q */
    const __hip_bfloat16* __restrict__ wb,   /* [bh][l][256] bf16 */
    const __hip_bfloat16* __restrict__ kTb,  /* [bh][c][s*32+i] bf16 */
    const __hip_bfloat16* __restrict__ attnb,/* [bh][c][i*32+j] bf16 */
    const float* __restrict__ u, float* __restrict__ delta /* == u region */) {
  __shared__ short Stb[64 * 264];
  __shared__ short U2T[64 * 40];
  const int bid = blockIdx.x;
  const int g = bid & 3;
  const int bh = bid >> 2;
  const int d0 = g * 64;
  const int t = threadIdx.x;
  const int wv = t >> 6, lane = t & 63;
  const int ln15 = lane & 15, qw = lane >> 4;
  const int kq = qw * 8, rbase = qw * 4;
  const int dv = wv * 16 + ln15;

  f4v Sacc[4][4];
#pragma unroll
  for (int mi = 0; mi < 4; ++mi)
#pragma unroll
    for (int nt = 0; nt < 4; ++nt) Sacc[mi][nt] = (f4v){0.f, 0.f, 0.f, 0.f};

  const short* wbase = (const short*)wb + (long)bh * SEQ * 256;
  const short* qbase = (const short*)qpk + (long)bh * SEQ * 256;
  const short* kTbase = (const short*)kTb + (long)bh * NCHUNK * 8192;
  const short* atbase = (const short*)attnb + (long)bh * NCHUNK * 1024;
  const float* ubase = u + (long)bh * SEQ * 256;
  float* dbase = delta + (long)bh * SEQ * 256;

  /* prefetch chunk 0 operands */
  s8v wpf0[8], wpf1[8], kpf[4];
  float upf0[4], upf1[4];
  {
    const short* wr0 = wbase + (long)ln15 * 256 + kq;
    const short* wr1 = wbase + (long)(16 + ln15) * 256 + kq;
#pragma unroll
    for (int ks = 0; ks < 8; ++ks) {
      wpf0[ks] = *(const s8v*)(wr0 + ks * 32);
      wpf1[ks] = *(const s8v*)(wr1 + ks * 32);
    }
#pragma unroll
    for (int mi = 0; mi < 4; ++mi)
      kpf[mi] = *(const s8v*)(kTbase + ((wv * 4 + mi) * 16 + ln15) * 32 + kq);
#pragma unroll
    for (int r = 0; r < 4; ++r) {
      upf0[r] = ubase[(long)(rbase + r) * 256 + d0 + dv];
      upf1[r] = ubase[(long)(16 + rbase + r) * 256 + d0 + dv];
    }
  }

  for (int c = 0; c < NCHUNK; ++c) {
    const int l0 = c * 32;
    /* (1) S -> Stb bf16 [dv][s] */
#pragma unroll
    for (int mi = 0; mi < 4; ++mi) {
      const int s0 = wv * 64 + mi * 16 + rbase;
#pragma unroll
      for (int nt = 0; nt < 4; ++nt) {
        ushort4 pk;
        pk.x = f2b(Sacc[mi][nt][0]);
        pk.y = f2b(Sacc[mi][nt][1]);
        pk.z = f2b(Sacc[mi][nt][2]);
        pk.w = f2b(Sacc[mi][nt][3]);
        *(ushort4*)&Stb[(nt * 16 + ln15) * 264 + s0] = pk;
      }
    }
    __syncthreads(); /* X */
    s8v bfr[8];
#pragma unroll
    for (int ks = 0; ks < 8; ++ks)
      bfr[ks] = *(const s8v*)&Stb[(wv * 16 + ln15) * 264 + ks * 32 + kq];
    /* issue q + attn loads now; consumed after Y */
    s8v qa0[8], qa1[8], at0, at1;
    {
      const short* qr0 = qbase + (long)(l0 + ln15) * 256 + kq;
      const short* qr1 = qbase + (long)(l0 + 16 + ln15) * 256 + kq;
#pragma unroll
      for (int ks = 0; ks < 8; ++ks) {
        qa0[ks] = *(const s8v*)(qr0 + ks * 32);
        qa1[ks] = *(const s8v*)(qr1 + ks * 32);
      }
      at0 = *(const s8v*)(atbase + (long)c * 1024 + ln15 * 32 + kq);
      at1 = *(const s8v*)(atbase + (long)c * 1024 + (16 + ln15) * 32 + kq);
    }
    /* (2) w@S with split chains (depth 4) */
    f4v dwA0 = (f4v){0.f, 0.f, 0.f, 0.f}, dwB0 = (f4v){0.f, 0.f, 0.f, 0.f};
    f4v dwA1 = (f4v){0.f, 0.f, 0.f, 0.f}, dwB1 = (f4v){0.f, 0.f, 0.f, 0.f};
#pragma unroll
    for (int ks = 0; ks < 4; ++ks) {
      dwA0 = __builtin_amdgcn_mfma_f32_16x16x32_bf16(wpf0[ks], bfr[ks], dwA0, 0, 0, 0);
      dwA1 = __builtin_amdgcn_mfma_f32_16x16x32_bf16(wpf1[ks], bfr[ks], dwA1, 0, 0, 0);
      dwB0 = __builtin_amdgcn_mfma_f32_16x16x32_bf16(wpf0[ks + 4], bfr[ks + 4], dwB0, 0, 0, 0);
      dwB1 = __builtin_amdgcn_mfma_f32_16x16x32_bf16(wpf1[ks + 4], bfr[ks + 4], dwB1, 0, 0, 0);
    }
    /* u2 = u - w@S, stash bf16 transposed */
    float u2a[4], u2b[4];
#pragma unroll
    for (int r = 0; r < 4; ++r) {
      u2a[r] = upf0[r] - (dwA0[r] + dwB0[r]);
      u2b[r] = upf1[r] - (dwA1[r] + dwB1[r]);
    }
    {
      ushort4 pa, pb;
      pa.x = f2b(u2a[0]); pa.y = f2b(u2a[1]); pa.z = f2b(u2a[2]); pa.w = f2b(u2a[3]);
      pb.x = f2b(u2b[0]); pb.y = f2b(u2b[1]); pb.z = f2b(u2b[2]); pb.w = f2b(u2b[3]);
      *(ushort4*)&U2T[dv * 40 + rbase] = pa;
      *(ushort4*)&U2T[dv * 40 + 16 + rbase] = pb;
    }
    /* prefetch w,u for c+1 */
    if (c + 1 < NCHUNK) {
      const short* nw0 = wbase + (long)(l0 + 32 + ln15) * 256 + kq;
      const short* nw1 = wbase + (long)(l0 + 48 + ln15) * 256 + kq;
#pragma unroll
      for (int ks = 0; ks < 8; ++ks) {
        wpf0[ks] = *(const s8v*)(nw0 + ks * 32);
        wpf1[ks] = *(const s8v*)(nw1 + ks * 32);
      }
#pragma unroll
      for (int r = 0; r < 4; ++r) {
        upf0[r] = ubase[(long)(l0 + 32 + rbase + r) * 256 + d0 + dv];
        upf1[r] = ubase[(long)(l0 + 48 + rbase + r) * 256 + d0 + dv];
      }
    }
    __syncthreads(); /* Y */
    /* (3) recurrence: S += kT@u2 */
    s8v bu[4];
#pragma unroll
    for (int nt = 0; nt < 4; ++nt)
      bu[nt] = *(const s8v*)&U2T[(nt * 16 + ln15) * 40 + kq];
#pragma unroll
    for (int mi = 0; mi < 4; ++mi)
#pragma unroll
      for (int nt = 0; nt < 4; ++nt)
        Sacc[mi][nt] = __builtin_amdgcn_mfma_f32_16x16x32_bf16(kpf[mi], bu[nt], Sacc[mi][nt], 0, 0, 0);
    /* prefetch kT for c+1 */
    if (c + 1 < NCHUNK) {
#pragma unroll
      for (int mi = 0; mi < 4; ++mi)
        kpf[mi] = *(const s8v*)(kTbase + (long)(c + 1) * 8192 + ((wv * 4 + mi) * 16 + ln15) * 32 + kq);
    }
    /* (4) output path: o = q@S + attn@u2 */
    f4v oA0 = (f4v){0.f, 0.f, 0.f, 0.f}, oB0 = (f4v){0.f, 0.f, 0.f, 0.f};
    f4v oA1 = (f4v){0.f, 0.f, 0.f, 0.f}, oB1 = (f4v){0.f, 0.f, 0.f, 0.f};
#pragma unroll
    for (int ks = 0; ks < 4; ++ks) {
      oA0 = __builtin_amdgcn_mfma_f32_16x16x32_bf16(qa0[ks], bfr[ks], oA0, 0, 0, 0);
      oA1 = __builtin_amdgcn_mfma_f32_16x16x32_bf16(qa1[ks], bfr[ks], oA1, 0, 0, 0);
      oB0 = __builtin_amdgcn_mfma_f32_16x16x32_bf16(qa0[ks + 4], bfr[ks + 4], oB0, 0, 0, 0);
      oB1 = __builtin_amdgcn_mfma_f32_16x16x32_bf16(qa1[ks + 4], bfr[ks + 4], oB1, 0, 0, 0);
    }
    oA0 = __builtin_amdgcn_mfma_f32_16x16x32_bf16(at0, bu[wv], oA0, 0, 0, 0);
    oA1 = __builtin_amdgcn_mfma_f32_16x16x32_bf16(at1, bu[wv], oA1, 0, 0, 0);
#pragma unroll
    for (int r = 0; r < 4; ++r) {
      dbase[(long)(l0 + rbase + r) * 256 + d0 + dv] = oA0[r] + oB0[r];
      dbase[(long)(l0 + 16 + rbase + r) * 256 + d0 + dv] = oA1[r] + oB1[r];
    }
    /* no tail barrier: next X orders Stb/U2T reuse */
  }
}

/* ---------- FIR v2: transposed [tap][ch] filters, coalesced, unrolled fast path ---------- */
__global__ __launch_bounds__(256) void fir_kernel(
    const float* __restrict__ v, const float* __restrict__ fsT,
    const float* __restrict__ flT, float* __restrict__ fs, float* __restrict__ fl) {
  const int row = blockIdx.x;
  const int l = row & (SEQ - 1);
  const int t = threadIdx.x;
  const int cb = t * 4;
  float4 accl = make_float4(0, 0, 0, 0);
  float4 accs = make_float4(0, 0, 0, 0);
  const float* vb = v + (long)(row - 30) * DMODEL + cb;
  if (l >= 30) {
#pragma unroll
    for (int j = 0; j < 31; ++j) {
      float4 w4 = *(const float4*)(flT + j * DMODEL + cb);
      float4 xv = *(const float4*)(vb + (long)j * DMODEL);
      accl.x = fmaf(w4.x, xv.x, accl.x);
      accl.y = fmaf(w4.y, xv.y, accl.y);
      accl.z = fmaf(w4.z, xv.z, accl.z);
      accl.w = fmaf(w4.w, xv.w, accl.w);
      if (j >= 28) {
        float4 s4 = *(const float4*)(fsT + (j - 28) * DMODEL + cb);
        accs.x = fmaf(s4.x, xv.x, accs.x);
        accs.y = fmaf(s4.y, xv.y, accs.y);
        accs.z = fmaf(s4.z, xv.z, accs.z);
        accs.w = fmaf(s4.w, xv.w, accs.w);
      }
    }
  } else {
    for (int j = 30 - l; j < 31; ++j) {
      float4 w4 = *(const float4*)(flT + j * DMODEL + cb);
      float4 xv = *(const float4*)(vb + (long)j * DMODEL);
      accl.x = fmaf(w4.x, xv.x, accl.x);
      accl.y = fmaf(w4.y, xv.y, accl.y);
      accl.z = fmaf(w4.z, xv.z, accl.z);
      accl.w = fmaf(w4.w, xv.w, accl.w);
      if (j >= 28) {
        float4 s4 = *(const float4*)(fsT + (j - 28) * DMODEL + cb);
        accs.x = fmaf(s4.x, xv.x, accs.x);
        accs.y = fmaf(s4.y, xv.y, accs.y);
        accs.z = fmaf(s4.z, xv.z, accs.z);
        accs.w = fmaf(s4.w, xv.w, accs.w);
      }
    }
  }
  *(float4*)(fs + (long)row * DMODEL + cb) = accs;
  *(float4*)(fl + (long)row * DMODEL + cb) = accl;
}

/* ---------- stats + assemble router input as bf16 (stride 1056, zero pad) ---------- */
__global__ __launch_bounds__(256) void stats_router(
    const float* __restrict__ x, const float* __restrict__ fs,
    const float* __restrict__ fl, const float* __restrict__ dl,
    __hip_bfloat16* __restrict__ rinb) {
  const int row = blockIdx.x;
  const int b = row >> 12;
  const int l = row & (SEQ - 1);
  const int t = threadIdx.x;
  float4 xv = *(const float4*)(x + (long)row * DMODEL + t * 4);
  {
    __hip_bfloat16 tmp[4] = {__float2bfloat16(xv.x), __float2bfloat16(xv.y),
                             __float2bfloat16(xv.z), __float2bfloat16(xv.w)};
    *(ushort4*)(rinb + (long)row * 1056 + t * 4) = *(ushort4*)tmp;
  }
  if (t < 8) rinb[(long)row * 1056 + 1048 + t] = __float2bfloat16(0.f);
  const int h = t >> 6;
  const int lane = t & 63;
  const long base = (long)row * DMODEL + h * DHEAD + lane * 4;
  const long dbase = ((long)(b * NH + h) * SEQ + l) * DHEAD + lane * 4;
  float4 a = *(const float4*)(fs + base);
  float4 bq = *(const float4*)(fl + base);
  float4 cq = *(const float4*)(dl + dbase);
  float s[6];
  s[0] = a.x + a.y + a.z + a.w;
  s[1] = a.x * a.x + a.y * a.y + a.z * a.z + a.w * a.w;
  s[2] = bq.x + bq.y + bq.z + bq.w;
  s[3] = bq.x * bq.x + bq.y * bq.y + bq.z * bq.z + bq.w * bq.w;
  s[4] = cq.x + cq.y + cq.z + cq.w;
  s[5] = cq.x * cq.x + cq.y * cq.y + cq.z * cq.z + cq.w * cq.w;
#pragma unroll
  for (int m = 1; m < 64; m <<= 1)
#pragma unroll
    for (int j = 0; j < 6; ++j) s[j] += __shfl_xor(s[j], m);
  if (lane == 0) {
    __hip_bfloat16* rb = rinb + (long)row * 1056 + 1024;
    float m0 = s[0] * (1.f / 256.f);
    float m1 = s[2] * (1.f / 256.f);
    float m2 = s[4] * (1.f / 256.f);
    rb[h] = __float2bfloat16(m0);
    rb[4 + h] = __float2bfloat16(sqrtf(fmaxf(s[1] * (1.f / 256.f) - m0 * m0, 0.f)));
    rb[8 + h] = __float2bfloat16(m1);
    rb[12 + h] = __float2bfloat16(sqrtf(fmaxf(s[3] * (1.f / 256.f) - m1 * m1, 0.f)));
    rb[16 + h] = __float2bfloat16(m2);
    rb[20 + h] = __float2bfloat16(sqrtf(fmaxf(s[5] * (1.f / 256.f) - m2 * m2, 0.f)));
  }
}

/* ---------- logits from bf16 hmid ; p = softmax(logits/tau)*0.925+0.025 ---------- */
__global__ __launch_bounds__(256) void router_logits(
    const __hip_bfloat16* __restrict__ hmid, const float* __restrict__ Wr2,
    const float* __restrict__ br2, const float* __restrict__ ltg, float* __restrict__ p) {
  const int row = blockIdx.x;
  const int t = threadIdx.x;
  float acc[12];
#pragma unroll
  for (int j = 0; j < 12; ++j) acc[j] = 0.f;
  const __hip_bfloat16* hr = hmid + (long)row * 2048;
  for (int k = t; k < 2048; k += 256) {
    float hv = __bfloat162float(hr[k]);
    const float* wr = Wr2 + k * 12;
#pragma unroll
    for (int j = 0; j < 12; ++j) acc[j] = fmaf(hv, wr[j], acc[j]);
  }
#pragma unroll
  for (int m = 1; m < 64; m <<= 1)
#pragma unroll
    for (int j = 0; j < 12; ++j) acc[j] += __shfl_xor(acc[j], m);
  __shared__ float red[4][12];
  if ((t & 63) == 0) {
    int wv = t >> 6;
#pragma unroll
    for (int j = 0; j < 12; ++j) red[wv][j] = acc[j];
  }
  __syncthreads();
  if (t < 4) {
    const int h = t;
    float l3[3];
#pragma unroll
    for (int j = 0; j < 3; ++j) {
      int col = h * 3 + j;
      l3[j] = red[0][col] + red[1][col] + red[2][col] + red[3][col] + br2[col];
    }
    float inv_tau = expf(-ltg[h >> 1]);
    float y0 = l3[0] * inv_tau, y1 = l3[1] * inv_tau, y2 = l3[2] * inv_tau;
    float mx = fmaxf(y0, fmaxf(y1, y2));
    float e0 = expf(y0 - mx), e1 = expf(y1 - mx), e2 = expf(y2 - mx);
    float inv = 1.f / (e0 + e1 + e2);
    p[(long)row * 12 + h * 3 + 0] = e0 * inv * 0.925f + 0.025f;
    p[(long)row * 12 + h * 3 + 1] = e1 * inv * 0.925f + 0.025f;
    p[(long)row * 12 + h * 3 + 2] = e2 * inv * 0.925f + 0.025f;
  }
}

/* ---------- mixture + identity + RMS norm -> bf16 out. delta layout (B,H,L,DV). ---------- */
__global__ __launch_bounds__(256) void omix(
    const float* __restrict__ fs, const float* __restrict__ fl,
    const float* __restrict__ dl, const float* __restrict__ vh,
    const float* __restrict__ p, const float* __restrict__ idsc,
    const float* __restrict__ onw, __hip_bfloat16* __restrict__ o) {
  const int row = blockIdx.x;
  const int b = row >> 12;
  const int l = row & (SEQ - 1);
  const int t = threadIdx.x;
  const int h = t >> 6;
  const int lane = t & 63;
  const long base = (long)row * DMODEL + h * DHEAD + lane * 4;
  const long dbase = ((long)(b * NH + h) * SEQ + l) * DHEAD + lane * 4;
  float p0 = p[(long)row * 12 + h * 3 + 0];
  float p1 = p[(long)row * 12 + h * 3 + 1];
  float p2 = p[(long)row * 12 + h * 3 + 2];
  float idv = idsc[(long)row * NH + h];
  float4 a = *(const float4*)(fs + base);
  float4 bq = *(const float4*)(fl + base);
  float4 cq = *(const float4*)(dl + dbase);
  float4 vv = *(const float4*)(vh + base);
  float4 ov;
  ov.x = p0 * a.x + p1 * bq.x + p2 * cq.x + idv * vv.x;
  ov.y = p0 * a.y + p1 * bq.y + p2 * cq.y + idv * vv.y;
  ov.z = p0 * a.z + p1 * bq.z + p2 * cq.z + idv * vv.z;
  ov.w = p0 * a.w + p1 * bq.w + p2 * cq.w + idv * vv.w;
  float ss = ov.x * ov.x + ov.y * ov.y + ov.z * ov.z + ov.w * ov.w;
#pragma unroll
  for (int m = 1; m < 64; m <<= 1) ss += __shfl_xor(ss, m);
  float rms = rsqrtf(ss * (1.f / 256.f) + 1e-5f);
  float4 wn = *(const float4*)(onw + lane * 4);
  __hip_bfloat16 tmp[4] = {__float2bfloat16(ov.x * rms * wn.x),
                           __float2bfloat16(ov.y * rms * wn.y),
                           __float2bfloat16(ov.z * rms * wn.z),
                           __float2bfloat16(ov.w * rms * wn.w)};
  *(ushort4*)(o + base) = *(ushort4*)tmp;
}

extern "C" void kernel_launch(void* const* d_in, const int* in_sizes, int n_in,
                              void* d_out, int out_size, void* d_ws, size_t ws_size,
                              hipStream_t stream) {
  const float* x = (const float*)d_in[0];
  const float* Wq = (const float*)d_in[1];
  const float* Wk = (const float*)d_in[2];
  const float* Wv = (const float*)d_in[3];
  const float* Wb = (const float*)d_in[4];
  const float* conv_q = (const float*)d_in[5];
  const float* conv_k = (const float*)d_in[6];
  const float* conv_v = (const float*)d_in[7];
  const float* fir_s = (const float*)d_in[8];
  const float* fir_l = (const float*)d_in[9];
  const float* alpha_id = (const float*)d_in[10];
  const float* Wid = (const float*)d_in[11];
  const float* bidp = (const float*)d_in[12];
  const float* Wr1 = (const float*)d_in[13];
  const float* br1 = (const float*)d_in[14];
  const float* Wr2 = (const float*)d_in[15];
  const float* br2 = (const float*)d_in[16];
  const float* ltg = (const float*)d_in[17];
  const float* onw = (const float*)d_in[19];
  const float* Wo = (const float*)d_in[20];

  /* workspace layout as round 5, plus transposed FIR filters at the tail */
  float* ws = (float*)d_ws;
  float* pre = ws + 0;
  float* ubuf = ws + 8388608;
  float* wbuf = ws + 16777216;
  float* attnbuf = ws + 25165824;
  float* qbuf = ws + 26214400;
  float* kbuf = ws + 34603008;
  float* vbuf = ws + 42991616;
  float* betabuf = ws + 51380224;
  float* idscbuf = ws + 51412992;
  float* pbuf = ws + 51445760;
  float* flTb = ws + 51544064;  /* 31*1024 */
  float* fsTb = ws + 51575808;  /* 3*1024, end 51578880 (~206.3 MB) */
  float* deltabuf = ubuf;
  __hip_bfloat16* xb = (__hip_bfloat16*)ubuf;
  __hip_bfloat16* Wqt = (__hip_bfloat16*)(wbuf);
  __hip_bfloat16* Wkt = (__hip_bfloat16*)(wbuf + 524288);
  __hip_bfloat16* Wvt = (__hip_bfloat16*)(wbuf + 1048576);
  __hip_bfloat16* wb16 = (__hip_bfloat16*)wbuf;
  __hip_bfloat16* kTb16 = (__hip_bfloat16*)wbuf + 8388608;
  __hip_bfloat16* attnb16 = (__hip_bfloat16*)attnbuf;
  __hip_bfloat16* qpk16 = (__hip_bfloat16*)pre;
  __hip_bfloat16* rinb = (__hip_bfloat16*)(wbuf);
  __hip_bfloat16* Wr1t = (__hip_bfloat16*)(wbuf + 4325376);
  __hip_bfloat16* Wot = (__hip_bfloat16*)(wbuf + 5406720);
  __hip_bfloat16* omixb = (__hip_bfloat16*)(wbuf);
  __hip_bfloat16* hmid = (__hip_bfloat16*)pre;
  float* fsb = qbuf;
  float* flb = kbuf;

  dim3 blk(256);
  cast_bf16<<<dim3(ROWS), blk, 0, stream>>>(x, xb);
  transpose_cast<<<dim3(32, 32), blk, 0, stream>>>(Wq, Wqt, 1024, 1024, 1024);
  transpose_cast<<<dim3(32, 32), blk, 0, stream>>>(Wk, Wkt, 1024, 1024, 1024);
  transpose_cast<<<dim3(32, 32), blk, 0, stream>>>(Wv, Wvt, 1024, 1024, 1024);
  fir_transpose<<<dim3(34), blk, 0, stream>>>(fir_s, fir_l, fsTb, flTb);
  gemm_bf16<0, false><<<dim3(8, 64), blk, 0, stream>>>(xb, Wqt, nullptr, pre, ROWS, 1024, 1024);
  conv_silu<<<dim3(ROWS), blk, 0, stream>>>(pre, conv_q, qbuf);
  gemm_bf16<0, false><<<dim3(8, 64), blk, 0, stream>>>(xb, Wkt, nullptr, pre, ROWS, 1024, 1024);
  conv_silu<<<dim3(ROWS), blk, 0, stream>>>(pre, conv_k, kbuf);
  gemm_bf16<0, false><<<dim3(8, 64), blk, 0, stream>>>(xb, Wvt, nullptr, pre, ROWS, 1024, 1024);
  conv_silu<<<dim3(ROWS), blk, 0, stream>>>(pre, conv_v, vbuf);
  rowdot8<<<dim3(ROWS), blk, 0, stream>>>(x, Wb, Wid, alpha_id, bidp, betabuf, idscbuf);
  l2norm_qk<<<dim3(ROWS), blk, 0, stream>>>(qbuf, kbuf, qpk16);
  phaseA<<<dim3(BATCH * NH * NCHUNK), blk, 0, stream>>>(qbuf, kbuf, vbuf, betabuf, ubuf, wb16, kTb16, attnb16);
  phaseB<<<dim3(BATCH * NH * 4), blk, 0, stream>>>(qpk16, wb16, kTb16, attnb16, ubuf, deltabuf);
  fir_kernel<<<dim3(ROWS), blk, 0, stream>>>(vbuf, fsTb, flTb, fsb, flb);
  stats_router<<<dim3(ROWS), blk, 0, stream>>>(x, fsb, flb, deltabuf, rinb);
  transpose_cast<<<dim3(64, 33), blk, 0, stream>>>(Wr1, Wr1t, 1048, 2048, 1056);
  transpose_cast<<<dim3(32, 32), blk, 0, stream>>>(Wo, Wot, 1024, 1024, 1024);
  gemm_bf16<1, true><<<dim3(16, 64), blk, 0, stream>>>(rinb, Wr1t, br1, hmid, ROWS, 2048, 1056);
  router_logits<<<dim3(ROWS), blk, 0, stream>>>(hmid, Wr2, br2, ltg, pbuf);
  omix<<<dim3(ROWS), blk, 0, stream>>>(fsb, flb, deltabuf, vbuf, pbuf, idscbuf, onw, omixb);
  gemm_bf16<0, false><<<dim3(8, 64), blk, 0, stream>>>(omixb, Wot, nullptr, d_out, ROWS, 1024, 1024);
}